// Round 1
// baseline (8012.283 us; speedup 1.0000x reference)
//
#include <hip/hip_runtime.h>

#define EPS 1e-5f

// ---------------- degree / norm setup ----------------

__global__ __launch_bounds__(256) void init_deg(float* deg, int n) {
    int i = blockIdx.x * 256 + threadIdx.x;
    if (i < n) deg[i] = 1.0f;   // self-loop
}

__global__ __launch_bounds__(256) void count_deg(const int* __restrict__ dst, float* deg, int E) {
    int i = blockIdx.x * 256 + threadIdx.x;
    if (i < E) atomicAdd(&deg[dst[i]], 1.0f);
}

__global__ __launch_bounds__(256) void calc_dis(const float* __restrict__ deg, float* __restrict__ dis, int n) {
    int i = blockIdx.x * 256 + threadIdx.x;
    if (i < n) dis[i] = rsqrtf(deg[i]);
}

__global__ __launch_bounds__(256) void calc_wnorm(const int* __restrict__ src, const int* __restrict__ dst,
                                                  const float* __restrict__ dis, float* __restrict__ wn, int E) {
    int i = blockIdx.x * 256 + threadIdx.x;
    if (i < E) wn[i] = dis[src[i]] * dis[dst[i]];
}

// ---------------- aggregation: out = A_norm @ x ----------------
// init: out[n][:] = x[n][:] * dis[n]^2   (self-loop term)
template<int D>
__global__ __launch_bounds__(256) void agg_init(const float* __restrict__ x, const float* __restrict__ dis,
                                                float* __restrict__ out, int n) {
    constexpr int C = D / 2;
    int gid = blockIdx.x * 256 + threadIdx.x;
    int node = gid / C, c = gid - node * C;
    if (node >= n) return;
    float dd = dis[node]; dd *= dd;
    float2 xv = *reinterpret_cast<const float2*>(x + (size_t)node * D + c * 2);
    float2 o; o.x = xv.x * dd; o.y = xv.y * dd;
    *reinterpret_cast<float2*>(out + (size_t)node * D + c * 2) = o;
}

// scatter: for each edge e: out[dst][:] += x[src][:] * wn[e]
template<int D, int VEC>
__global__ __launch_bounds__(256) void agg_scatter(const float* __restrict__ x, const int* __restrict__ src,
                                                   const int* __restrict__ dst, const float* __restrict__ wn,
                                                   float* __restrict__ out, int E) {
    constexpr int CPE = D / VEC;
    int gid = blockIdx.x * 256 + threadIdx.x;
    int e = gid / CPE, c = gid - e * CPE;
    if (e >= E) return;
    int s = src[e], d = dst[e];
    float w = wn[e];
    if (VEC == 4) {
        float4 xv = *reinterpret_cast<const float4*>(x + (size_t)s * D + c * 4);
        float* op = out + (size_t)d * D + c * 4;
        atomicAdd(op + 0, xv.x * w);
        atomicAdd(op + 1, xv.y * w);
        atomicAdd(op + 2, xv.z * w);
        atomicAdd(op + 3, xv.w * w);
    } else {
        float2 xv = *reinterpret_cast<const float2*>(x + (size_t)s * D + c * 2);
        float* op = out + (size_t)d * D + c * 2;
        atomicAdd(op + 0, xv.x * w);
        atomicAdd(op + 1, xv.y * w);
    }
}

// ---------------- fused GEMM: out = epilogue(X @ W) ----------------
// MODE 0: z=(acc+b)*s+t, relu      (GCN layer, aggregate-first)
// MODE 1: z=acc*s                   (transform-first pre-aggregation)
// MODE 2: z=relu(acc+b)*s+t        (classifier Linear->ReLU->BN)
template<int K, int DOUT, int RPT, int MODE>
__global__ __launch_bounds__(256) void gemm_fused(const float* __restrict__ X, const float* __restrict__ W,
                                                  const float* __restrict__ b, const float* __restrict__ g,
                                                  const float* __restrict__ be, const float* __restrict__ rm,
                                                  const float* __restrict__ rv, float* __restrict__ out, int nrows) {
    constexpr int G = 256 / DOUT;       // row groups per block
    constexpr int ROWS = RPT * G;       // rows per block
    __shared__ float xs[ROWS][K + 1];   // +1 pad: break bank aliasing across groups
    const int tid = threadIdx.x;
    const int col = tid % DOUT;
    const int grp = tid / DOUT;
    const int row0 = blockIdx.x * ROWS;

    for (int i = tid; i < ROWS * K; i += 256) {
        int r = i / K, k = i - r * K;
        int rr = row0 + r;
        xs[r][k] = (rr < nrows) ? X[(size_t)rr * K + k] : 0.0f;
    }
    __syncthreads();

    float acc[RPT];
#pragma unroll
    for (int r = 0; r < RPT; ++r) acc[r] = 0.0f;

#pragma unroll 4
    for (int k = 0; k < K; ++k) {
        float w = W[(size_t)k * DOUT + col];
#pragma unroll
        for (int r = 0; r < RPT; ++r)
            acc[r] = fmaf(xs[grp * RPT + r][k], w, acc[r]);
    }

    float s = 1.0f, t = 0.0f, bias = 0.0f;
    if (MODE == 0 || MODE == 2) {
        float sv = g[col] * rsqrtf(rv[col] + EPS);
        s = sv; t = be[col] - rm[col] * sv; bias = b[col];
    } else if (MODE == 1) {
        s = g[col] * rsqrtf(rv[col] + EPS);
    }

#pragma unroll
    for (int r = 0; r < RPT; ++r) {
        int rr = row0 + grp * RPT + r;
        if (rr < nrows) {
            float z = acc[r];
            if (MODE == 0)      { z = (z + bias) * s + t; z = fmaxf(z, 0.0f); }
            else if (MODE == 1) { z = z * s; }
            else                { z = fmaxf(z + bias, 0.0f) * s + t; }
            out[(size_t)rr * DOUT + col] = z;
        }
    }
}

// elementwise: h = relu(h + (b*s + t))  -- post-aggregation epilogue (transform-first layers)
template<int D>
__global__ __launch_bounds__(256) void bias_bn_relu(float* __restrict__ h, const float* __restrict__ b,
                                                    const float* __restrict__ g, const float* __restrict__ be,
                                                    const float* __restrict__ rm, const float* __restrict__ rv, int n) {
    int gid = blockIdx.x * 256 + threadIdx.x;
    if (gid >= n * D) return;
    int col = gid % D;
    float sv = g[col] * rsqrtf(rv[col] + EPS);
    float bb = b[col] * sv + (be[col] - rm[col] * sv);
    h[gid] = fmaxf(h[gid] + bb, 0.0f);
}

// final Linear 32 -> 2
__global__ __launch_bounds__(256) void final_linear(const float* __restrict__ X, const float* __restrict__ W,
                                                    const float* __restrict__ b, float* __restrict__ out, int n) {
    int row = blockIdx.x * 256 + threadIdx.x;
    if (row >= n) return;
    float a0 = 0.0f, a1 = 0.0f;
#pragma unroll
    for (int k = 0; k < 32; ++k) {
        float xv = X[(size_t)row * 32 + k];
        a0 = fmaf(xv, W[k * 2 + 0], a0);
        a1 = fmaf(xv, W[k * 2 + 1], a1);
    }
    out[(size_t)row * 2 + 0] = a0 + b[0];
    out[(size_t)row * 2 + 1] = a1 + b[1];
}

// ---------------- launch ----------------

extern "C" void kernel_launch(void* const* d_in, const int* in_sizes, int n_in,
                              void* d_out, int out_size, void* d_ws, size_t ws_size,
                              hipStream_t stream) {
    const float* x  = (const float*)d_in[0];
    const int*   ei = (const int*)d_in[1];
    const int E = in_sizes[1] / 2;
    const int n = in_sizes[0] / 42;
    const int* src = ei;
    const int* dst = ei + E;

    const float *W1 = (const float*)d_in[2],  *b1 = (const float*)d_in[3],  *g1 = (const float*)d_in[4],
                *be1 = (const float*)d_in[5], *rm1 = (const float*)d_in[6], *rv1 = (const float*)d_in[7];
    const float *W2 = (const float*)d_in[8],  *b2 = (const float*)d_in[9],  *g2 = (const float*)d_in[10],
                *be2 = (const float*)d_in[11], *rm2 = (const float*)d_in[12], *rv2 = (const float*)d_in[13];
    const float *W3 = (const float*)d_in[14], *b3 = (const float*)d_in[15], *g3 = (const float*)d_in[16],
                *be3 = (const float*)d_in[17], *rm3 = (const float*)d_in[18], *rv3 = (const float*)d_in[19];
    const float *W4 = (const float*)d_in[20], *b4 = (const float*)d_in[21], *g4 = (const float*)d_in[22],
                *be4 = (const float*)d_in[23], *rm4 = (const float*)d_in[24], *rv4 = (const float*)d_in[25];
    const float *cW1 = (const float*)d_in[26], *cb1 = (const float*)d_in[27], *cg1 = (const float*)d_in[28],
                *cbe1 = (const float*)d_in[29], *crm1 = (const float*)d_in[30], *crv1 = (const float*)d_in[31];
    const float *cW2 = (const float*)d_in[32], *cb2 = (const float*)d_in[33], *cg2 = (const float*)d_in[34],
                *cbe2 = (const float*)d_in[35], *crm2 = (const float*)d_in[36], *crv2 = (const float*)d_in[37];
    const float *cW3 = (const float*)d_in[38], *cb3 = (const float*)d_in[39];

    float* bufA = (float*)d_ws;                 // n*256
    float* bufB = bufA + (size_t)n * 256;       // n*256
    float* deg  = bufB + (size_t)n * 256;       // n
    float* dis  = deg + n;                      // n
    float* wn   = dis + n;                      // E

    dim3 blk(256);
    auto nb = [](long total) { return dim3((unsigned)((total + 255) / 256)); };

    // degrees / edge norms
    init_deg<<<nb(n), blk, 0, stream>>>(deg, n);
    count_deg<<<nb(E), blk, 0, stream>>>(dst, deg, E);
    calc_dis<<<nb(n), blk, 0, stream>>>(deg, dis, n);
    calc_wnorm<<<nb(E), blk, 0, stream>>>(src, dst, dis, wn, E);

    // ---- Layer 1 (aggregate-first, d=42): agg(x) -> bufA; gemm 42->128 BN+ReLU -> bufB
    agg_init<42><<<nb((long)n * 21), blk, 0, stream>>>(x, dis, bufA, n);
    agg_scatter<42, 2><<<nb((long)E * 21), blk, 0, stream>>>(x, src, dst, wn, bufA, E);
    gemm_fused<42, 128, 8, 0><<<dim3((n + 15) / 16), blk, 0, stream>>>(bufA, W1, b1, g1, be1, rm1, rv1, bufB, n);

    // ---- Layer 2 (aggregate-first, d=128): agg(bufB) -> bufA; gemm 128->256 BN+ReLU -> bufB
    agg_init<128><<<nb((long)n * 64), blk, 0, stream>>>(bufB, dis, bufA, n);
    agg_scatter<128, 4><<<nb((long)E * 32), blk, 0, stream>>>(bufB, src, dst, wn, bufA, E);
    gemm_fused<128, 256, 8, 0><<<dim3((n + 7) / 8), blk, 0, stream>>>(bufA, W2, b2, g2, be2, rm2, rv2, bufB, n);

    // ---- Layer 3 (transform-first): gemm 256->128 (scale by s) bufB->bufA; agg -> bufB; +b'' relu
    gemm_fused<256, 128, 8, 1><<<dim3((n + 15) / 16), blk, 0, stream>>>(bufB, W3, b3, g3, be3, rm3, rv3, bufA, n);
    agg_init<128><<<nb((long)n * 64), blk, 0, stream>>>(bufA, dis, bufB, n);
    agg_scatter<128, 4><<<nb((long)E * 32), blk, 0, stream>>>(bufA, src, dst, wn, bufB, E);
    bias_bn_relu<128><<<nb((long)n * 128), blk, 0, stream>>>(bufB, b3, g3, be3, rm3, rv3, n);

    // ---- Layer 4 (transform-first): gemm 128->64 (scale) bufB->bufA; agg -> bufB; +b'' relu
    gemm_fused<128, 64, 8, 1><<<dim3((n + 31) / 32), blk, 0, stream>>>(bufB, W4, b4, g4, be4, rm4, rv4, bufA, n);
    agg_init<64><<<nb((long)n * 32), blk, 0, stream>>>(bufA, dis, bufB, n);
    agg_scatter<64, 4><<<nb((long)E * 16), blk, 0, stream>>>(bufA, src, dst, wn, bufB, E);
    bias_bn_relu<64><<<nb((long)n * 64), blk, 0, stream>>>(bufB, b4, g4, be4, rm4, rv4, n);

    // ---- Classifier
    gemm_fused<64, 64, 8, 2><<<dim3((n + 31) / 32), blk, 0, stream>>>(bufB, cW1, cb1, cg1, cbe1, crm1, crv1, bufA, n);
    gemm_fused<64, 32, 8, 2><<<dim3((n + 63) / 64), blk, 0, stream>>>(bufA, cW2, cb2, cg2, cbe2, crm2, crv2, bufB, n);
    final_linear<<<nb(n), blk, 0, stream>>>(bufB, cW3, cb3, (float*)d_out, n);
}

// Round 2
// 1059.990 us; speedup vs baseline: 7.5588x; 7.5588x over previous
//
#include <hip/hip_runtime.h>

#define EPS 1e-5f

// ---------------- degree count ----------------

__global__ __launch_bounds__(256) void count_deg(const int* __restrict__ dst, int* __restrict__ cnt, int E) {
    int i = blockIdx.x * 256 + threadIdx.x;
    if (i < E) atomicAdd(&cnt[dst[i]], 1);
}

__global__ __launch_bounds__(256) void calc_dis(const int* __restrict__ cnt, float* __restrict__ dis, int n) {
    int i = blockIdx.x * 256 + threadIdx.x;
    if (i < n) dis[i] = rsqrtf((float)cnt[i] + 1.0f);
}

// ---------------- exclusive scan (3-kernel): rowptr = exscan(cnt) ----------------
// scan1: 256 threads x 4 elems = 1024 per block
__global__ __launch_bounds__(256) void scan1(const int* __restrict__ cnt, int* __restrict__ excl,
                                             int* __restrict__ bsum, int n) {
    __shared__ int sdata[256];
    const int tid = threadIdx.x;
    const int base = blockIdx.x * 1024 + tid * 4;
    int v0 = (base + 0 < n) ? cnt[base + 0] : 0;
    int v1 = (base + 1 < n) ? cnt[base + 1] : 0;
    int v2 = (base + 2 < n) ? cnt[base + 2] : 0;
    int v3 = (base + 3 < n) ? cnt[base + 3] : 0;
    int s = v0 + v1 + v2 + v3;
    sdata[tid] = s;
    __syncthreads();
    for (int off = 1; off < 256; off <<= 1) {
        int t = (tid >= off) ? sdata[tid - off] : 0;
        __syncthreads();
        sdata[tid] += t;
        __syncthreads();
    }
    if (tid == 255) bsum[blockIdx.x] = sdata[255];
    int run = sdata[tid] - s;   // exclusive prefix of this thread's 4 elems
    if (base + 0 < n) excl[base + 0] = run; run += v0;
    if (base + 1 < n) excl[base + 1] = run; run += v1;
    if (base + 2 < n) excl[base + 2] = run; run += v2;
    if (base + 3 < n) excl[base + 3] = run;
}

__global__ __launch_bounds__(256) void scan2(int* __restrict__ bsum, int nb) {
    __shared__ int sdata[256];
    const int tid = threadIdx.x;
    int v = (tid < nb) ? bsum[tid] : 0;
    sdata[tid] = v;
    __syncthreads();
    for (int off = 1; off < 256; off <<= 1) {
        int t = (tid >= off) ? sdata[tid - off] : 0;
        __syncthreads();
        sdata[tid] += t;
        __syncthreads();
    }
    if (tid < nb) bsum[tid] = sdata[tid] - v;   // exclusive
}

__global__ __launch_bounds__(256) void scan3(int* __restrict__ rowptr, const int* __restrict__ bsum, int n, int E) {
    int i = blockIdx.x * 256 + threadIdx.x;
    if (i < n) rowptr[i] += bsum[i >> 10];
    if (i == 0) rowptr[n] = E;
}

// ---------------- CSR fill: csr[pos] = (src, w) sorted by dst ----------------
__global__ __launch_bounds__(256) void csr_fill(const int* __restrict__ src, const int* __restrict__ dst,
                                                const float* __restrict__ dis, const int* __restrict__ rowptr,
                                                int* __restrict__ fill, int2* __restrict__ csr, int E) {
    int e = blockIdx.x * 256 + threadIdx.x;
    if (e >= E) return;
    int s = src[e], d = dst[e];
    int pos = rowptr[d] + atomicAdd(&fill[d], 1);
    csr[pos] = make_int2(s, __float_as_int(dis[s] * dis[d]));
}

// ---------------- aggregation (gather): out[nd] = dis[nd]^2*x[nd] + sum_e w_e * x[src_e] ----------------
template<int D, int VEC>
__global__ __launch_bounds__(256) void agg_gather(const float* __restrict__ x, const float* __restrict__ dis,
                                                  const int* __restrict__ rowptr, const int2* __restrict__ csr,
                                                  float* __restrict__ out, int n) {
    constexpr int CPE = D / VEC;
    int gid = blockIdx.x * 256 + threadIdx.x;
    int nd = gid / CPE, c = gid - nd * CPE;
    if (nd >= n) return;
    float dd = dis[nd]; dd *= dd;

    float acc0, acc1, acc2, acc3;
    if (VEC == 4) {
        float4 v = *reinterpret_cast<const float4*>(x + (size_t)nd * D + c * 4);
        acc0 = v.x * dd; acc1 = v.y * dd; acc2 = v.z * dd; acc3 = v.w * dd;
    } else {
        float2 v = *reinterpret_cast<const float2*>(x + (size_t)nd * D + c * 2);
        acc0 = v.x * dd; acc1 = v.y * dd; acc2 = 0.0f; acc3 = 0.0f;
    }

    int r0 = rowptr[nd], r1 = rowptr[nd + 1];
    for (int i = r0; i < r1; ++i) {
        int2 sw = csr[i];
        float w = __int_as_float(sw.y);
        if (VEC == 4) {
            float4 v = *reinterpret_cast<const float4*>(x + (size_t)sw.x * D + c * 4);
            acc0 = fmaf(v.x, w, acc0); acc1 = fmaf(v.y, w, acc1);
            acc2 = fmaf(v.z, w, acc2); acc3 = fmaf(v.w, w, acc3);
        } else {
            float2 v = *reinterpret_cast<const float2*>(x + (size_t)sw.x * D + c * 2);
            acc0 = fmaf(v.x, w, acc0); acc1 = fmaf(v.y, w, acc1);
        }
    }

    if (VEC == 4) {
        float4 o; o.x = acc0; o.y = acc1; o.z = acc2; o.w = acc3;
        *reinterpret_cast<float4*>(out + (size_t)nd * D + c * 4) = o;
    } else {
        float2 o; o.x = acc0; o.y = acc1;
        *reinterpret_cast<float2*>(out + (size_t)nd * D + c * 2) = o;
    }
}

// ---------------- fused GEMM: out = epilogue(X @ W) ----------------
// MODE 0: z=(acc+b)*s+t, relu      (GCN layer, aggregate-first)
// MODE 1: z=acc*s                   (transform-first pre-aggregation)
// MODE 2: z=relu(acc+b)*s+t        (classifier Linear->ReLU->BN)
template<int K, int DOUT, int RPT, int MODE>
__global__ __launch_bounds__(256) void gemm_fused(const float* __restrict__ X, const float* __restrict__ W,
                                                  const float* __restrict__ b, const float* __restrict__ g,
                                                  const float* __restrict__ be, const float* __restrict__ rm,
                                                  const float* __restrict__ rv, float* __restrict__ out, int nrows) {
    constexpr int G = 256 / DOUT;       // row groups per block
    constexpr int ROWS = RPT * G;       // rows per block
    __shared__ float xs[ROWS][K + 1];
    const int tid = threadIdx.x;
    const int col = tid % DOUT;
    const int grp = tid / DOUT;
    const int row0 = blockIdx.x * ROWS;

    for (int i = tid; i < ROWS * K; i += 256) {
        int r = i / K, k = i - r * K;
        int rr = row0 + r;
        xs[r][k] = (rr < nrows) ? X[(size_t)rr * K + k] : 0.0f;
    }
    __syncthreads();

    float acc[RPT];
#pragma unroll
    for (int r = 0; r < RPT; ++r) acc[r] = 0.0f;

#pragma unroll 4
    for (int k = 0; k < K; ++k) {
        float w = W[(size_t)k * DOUT + col];
#pragma unroll
        for (int r = 0; r < RPT; ++r)
            acc[r] = fmaf(xs[grp * RPT + r][k], w, acc[r]);
    }

    float s = 1.0f, t = 0.0f, bias = 0.0f;
    if (MODE == 0 || MODE == 2) {
        float sv = g[col] * rsqrtf(rv[col] + EPS);
        s = sv; t = be[col] - rm[col] * sv; bias = b[col];
    } else if (MODE == 1) {
        s = g[col] * rsqrtf(rv[col] + EPS);
    }

#pragma unroll
    for (int r = 0; r < RPT; ++r) {
        int rr = row0 + grp * RPT + r;
        if (rr < nrows) {
            float z = acc[r];
            if (MODE == 0)      { z = (z + bias) * s + t; z = fmaxf(z, 0.0f); }
            else if (MODE == 1) { z = z * s; }
            else                { z = fmaxf(z + bias, 0.0f) * s + t; }
            out[(size_t)rr * DOUT + col] = z;
        }
    }
}

// elementwise: h = relu(h + (b*s + t))  -- post-aggregation epilogue (transform-first layers)
template<int D>
__global__ __launch_bounds__(256) void bias_bn_relu(float* __restrict__ h, const float* __restrict__ b,
                                                    const float* __restrict__ g, const float* __restrict__ be,
                                                    const float* __restrict__ rm, const float* __restrict__ rv, int n) {
    int gid = blockIdx.x * 256 + threadIdx.x;
    if (gid >= n * D) return;
    int col = gid % D;
    float sv = g[col] * rsqrtf(rv[col] + EPS);
    float bb = b[col] * sv + (be[col] - rm[col] * sv);
    h[gid] = fmaxf(h[gid] + bb, 0.0f);
}

// final Linear 32 -> 2
__global__ __launch_bounds__(256) void final_linear(const float* __restrict__ X, const float* __restrict__ W,
                                                    const float* __restrict__ b, float* __restrict__ out, int n) {
    int row = blockIdx.x * 256 + threadIdx.x;
    if (row >= n) return;
    float a0 = 0.0f, a1 = 0.0f;
#pragma unroll
    for (int k = 0; k < 32; ++k) {
        float xv = X[(size_t)row * 32 + k];
        a0 = fmaf(xv, W[k * 2 + 0], a0);
        a1 = fmaf(xv, W[k * 2 + 1], a1);
    }
    out[(size_t)row * 2 + 0] = a0 + b[0];
    out[(size_t)row * 2 + 1] = a1 + b[1];
}

// ---------------- launch ----------------

extern "C" void kernel_launch(void* const* d_in, const int* in_sizes, int n_in,
                              void* d_out, int out_size, void* d_ws, size_t ws_size,
                              hipStream_t stream) {
    const float* x  = (const float*)d_in[0];
    const int*   ei = (const int*)d_in[1];
    const int E = in_sizes[1] / 2;
    const int n = in_sizes[0] / 42;
    const int* src = ei;
    const int* dst = ei + E;

    const float *W1 = (const float*)d_in[2],  *b1 = (const float*)d_in[3],  *g1 = (const float*)d_in[4],
                *be1 = (const float*)d_in[5], *rm1 = (const float*)d_in[6], *rv1 = (const float*)d_in[7];
    const float *W2 = (const float*)d_in[8],  *b2 = (const float*)d_in[9],  *g2 = (const float*)d_in[10],
                *be2 = (const float*)d_in[11], *rm2 = (const float*)d_in[12], *rv2 = (const float*)d_in[13];
    const float *W3 = (const float*)d_in[14], *b3 = (const float*)d_in[15], *g3 = (const float*)d_in[16],
                *be3 = (const float*)d_in[17], *rm3 = (const float*)d_in[18], *rv3 = (const float*)d_in[19];
    const float *W4 = (const float*)d_in[20], *b4 = (const float*)d_in[21], *g4 = (const float*)d_in[22],
                *be4 = (const float*)d_in[23], *rm4 = (const float*)d_in[24], *rv4 = (const float*)d_in[25];
    const float *cW1 = (const float*)d_in[26], *cb1 = (const float*)d_in[27], *cg1 = (const float*)d_in[28],
                *cbe1 = (const float*)d_in[29], *crm1 = (const float*)d_in[30], *crv1 = (const float*)d_in[31];
    const float *cW2 = (const float*)d_in[32], *cb2 = (const float*)d_in[33], *cg2 = (const float*)d_in[34],
                *cbe2 = (const float*)d_in[35], *crm2 = (const float*)d_in[36], *crv2 = (const float*)d_in[37];
    const float *cW3 = (const float*)d_in[38], *cb3 = (const float*)d_in[39];

    // ---- workspace layout (csr first for 8B alignment) ----
    int2*  csr    = (int2*)d_ws;                       // E
    float* bufA   = (float*)(csr + E);                 // n*128
    float* bufB   = bufA + (size_t)n * 128;            // n*256
    float* dis    = bufB + (size_t)n * 256;            // n
    int*   cnt    = (int*)(dis + n);                   // n
    int*   fill   = cnt + n;                           // n   (contiguous with cnt -> single memset)
    int*   rowptr = fill + n;                          // n+1
    int*   bsum   = rowptr + n + 1;                    // 256

    dim3 blk(256);
    auto nb = [](long total) { return dim3((unsigned)((total + 255) / 256)); };
    const int nscan = (n + 1023) / 1024;

    // ---- CSR build ----
    hipMemsetAsync(cnt, 0, (size_t)2 * n * sizeof(int), stream);   // cnt + fill
    count_deg<<<nb(E), blk, 0, stream>>>(dst, cnt, E);
    calc_dis<<<nb(n), blk, 0, stream>>>(cnt, dis, n);
    scan1<<<dim3(nscan), blk, 0, stream>>>(cnt, rowptr, bsum, n);
    scan2<<<dim3(1), blk, 0, stream>>>(bsum, nscan);
    scan3<<<nb(n), blk, 0, stream>>>(rowptr, bsum, n, E);
    csr_fill<<<nb(E), blk, 0, stream>>>(src, dst, dis, rowptr, fill, csr, E);

    // ---- Layer 1 (aggregate-first, d=42): agg(x) -> bufA; gemm 42->128 BN+ReLU -> bufB
    agg_gather<42, 2><<<nb((long)n * 21), blk, 0, stream>>>(x, dis, rowptr, csr, bufA, n);
    gemm_fused<42, 128, 8, 0><<<dim3((n + 15) / 16), blk, 0, stream>>>(bufA, W1, b1, g1, be1, rm1, rv1, bufB, n);

    // ---- Layer 2 (aggregate-first, d=128): agg(bufB) -> bufA; gemm 128->256 BN+ReLU -> bufB
    agg_gather<128, 4><<<nb((long)n * 32), blk, 0, stream>>>(bufB, dis, rowptr, csr, bufA, n);
    gemm_fused<128, 256, 8, 0><<<dim3((n + 7) / 8), blk, 0, stream>>>(bufA, W2, b2, g2, be2, rm2, rv2, bufB, n);

    // ---- Layer 3 (transform-first): gemm 256->128 (scale by s) bufB->bufA; agg -> bufB; +b'' relu
    gemm_fused<256, 128, 8, 1><<<dim3((n + 15) / 16), blk, 0, stream>>>(bufB, W3, b3, g3, be3, rm3, rv3, bufA, n);
    agg_gather<128, 4><<<nb((long)n * 32), blk, 0, stream>>>(bufA, dis, rowptr, csr, bufB, n);
    bias_bn_relu<128><<<nb((long)n * 128), blk, 0, stream>>>(bufB, b3, g3, be3, rm3, rv3, n);

    // ---- Layer 4 (transform-first): gemm 128->64 (scale) bufB->bufA; agg -> bufB; +b'' relu
    gemm_fused<128, 64, 8, 1><<<dim3((n + 31) / 32), blk, 0, stream>>>(bufB, W4, b4, g4, be4, rm4, rv4, bufA, n);
    agg_gather<64, 4><<<nb((long)n * 16), blk, 0, stream>>>(bufA, dis, rowptr, csr, bufB, n);
    bias_bn_relu<64><<<nb((long)n * 64), blk, 0, stream>>>(bufB, b4, g4, be4, rm4, rv4, n);

    // ---- Classifier
    gemm_fused<64, 64, 8, 2><<<dim3((n + 31) / 32), blk, 0, stream>>>(bufB, cW1, cb1, cg1, cbe1, crm1, crv1, bufA, n);
    gemm_fused<64, 32, 8, 2><<<dim3((n + 63) / 64), blk, 0, stream>>>(bufA, cW2, cb2, cg2, cbe2, crm2, crv2, bufB, n);
    final_linear<<<nb(n), blk, 0, stream>>>(bufB, cW3, cb3, (float*)d_out, n);
}

// Round 3
// 846.010 us; speedup vs baseline: 9.4707x; 1.2529x over previous
//
#include <hip/hip_runtime.h>

#define EPS 1e-5f

// ---------------- degree count ----------------

__global__ __launch_bounds__(256) void count_deg(const int* __restrict__ dst, int* __restrict__ cnt, int E) {
    int i = blockIdx.x * 256 + threadIdx.x;
    if (i < E) atomicAdd(&cnt[dst[i]], 1);
}

__global__ __launch_bounds__(256) void calc_dis(const int* __restrict__ cnt, float* __restrict__ dis, int n) {
    int i = blockIdx.x * 256 + threadIdx.x;
    if (i < n) dis[i] = rsqrtf((float)cnt[i] + 1.0f);
}

// ---------------- exclusive scan (3-kernel): rowptr = exscan(cnt) ----------------
__global__ __launch_bounds__(256) void scan1(const int* __restrict__ cnt, int* __restrict__ excl,
                                             int* __restrict__ bsum, int n) {
    __shared__ int sdata[256];
    const int tid = threadIdx.x;
    const int base = blockIdx.x * 1024 + tid * 4;
    int v0 = (base + 0 < n) ? cnt[base + 0] : 0;
    int v1 = (base + 1 < n) ? cnt[base + 1] : 0;
    int v2 = (base + 2 < n) ? cnt[base + 2] : 0;
    int v3 = (base + 3 < n) ? cnt[base + 3] : 0;
    int s = v0 + v1 + v2 + v3;
    sdata[tid] = s;
    __syncthreads();
    for (int off = 1; off < 256; off <<= 1) {
        int t = (tid >= off) ? sdata[tid - off] : 0;
        __syncthreads();
        sdata[tid] += t;
        __syncthreads();
    }
    if (tid == 255) bsum[blockIdx.x] = sdata[255];
    int run = sdata[tid] - s;
    if (base + 0 < n) excl[base + 0] = run; run += v0;
    if (base + 1 < n) excl[base + 1] = run; run += v1;
    if (base + 2 < n) excl[base + 2] = run; run += v2;
    if (base + 3 < n) excl[base + 3] = run;
}

__global__ __launch_bounds__(256) void scan2(int* __restrict__ bsum, int nb) {
    __shared__ int sdata[256];
    const int tid = threadIdx.x;
    int v = (tid < nb) ? bsum[tid] : 0;
    sdata[tid] = v;
    __syncthreads();
    for (int off = 1; off < 256; off <<= 1) {
        int t = (tid >= off) ? sdata[tid - off] : 0;
        __syncthreads();
        sdata[tid] += t;
        __syncthreads();
    }
    if (tid < nb) bsum[tid] = sdata[tid] - v;
}

__global__ __launch_bounds__(256) void scan3(int* __restrict__ rowptr, const int* __restrict__ bsum, int n, int E) {
    int i = blockIdx.x * 256 + threadIdx.x;
    if (i < n) rowptr[i] += bsum[i >> 10];
    if (i == 0) rowptr[n] = E;
}

// ---------------- CSR fill ----------------
__global__ __launch_bounds__(256) void csr_fill(const int* __restrict__ src, const int* __restrict__ dst,
                                                const float* __restrict__ dis, const int* __restrict__ rowptr,
                                                int* __restrict__ fill, int2* __restrict__ csr, int E) {
    int e = blockIdx.x * 256 + threadIdx.x;
    if (e >= E) return;
    int s = src[e], d = dst[e];
    int pos = rowptr[d] + atomicAdd(&fill[d], 1);
    csr[pos] = make_int2(s, __float_as_int(dis[s] * dis[d]));
}

// ---------------- aggregation (gather) ----------------
// FUSE 0: out = A_norm @ x
// FUSE 1: out = relu(A_norm @ x + (b*s + t))   (post-agg epilogue of transform-first layers)
template<int D, int VEC, int FUSE>
__global__ __launch_bounds__(256) void agg_gather(const float* __restrict__ x, const float* __restrict__ dis,
                                                  const int* __restrict__ rowptr, const int2* __restrict__ csr,
                                                  const float* __restrict__ b, const float* __restrict__ g,
                                                  const float* __restrict__ be, const float* __restrict__ rm,
                                                  const float* __restrict__ rv,
                                                  float* __restrict__ out, int n) {
    constexpr int CPE = D / VEC;
    int gid = blockIdx.x * 256 + threadIdx.x;
    int nd = gid / CPE, c = gid - nd * CPE;
    if (nd >= n) return;
    float dd = dis[nd]; dd *= dd;

    float acc0, acc1, acc2, acc3;
    if (VEC == 4) {
        float4 v = *reinterpret_cast<const float4*>(x + (size_t)nd * D + c * 4);
        acc0 = v.x * dd; acc1 = v.y * dd; acc2 = v.z * dd; acc3 = v.w * dd;
    } else {
        float2 v = *reinterpret_cast<const float2*>(x + (size_t)nd * D + c * 2);
        acc0 = v.x * dd; acc1 = v.y * dd; acc2 = 0.0f; acc3 = 0.0f;
    }

    int r0 = rowptr[nd], r1 = rowptr[nd + 1];
    for (int i = r0; i < r1; ++i) {
        int2 sw = csr[i];
        float w = __int_as_float(sw.y);
        if (VEC == 4) {
            float4 v = *reinterpret_cast<const float4*>(x + (size_t)sw.x * D + c * 4);
            acc0 = fmaf(v.x, w, acc0); acc1 = fmaf(v.y, w, acc1);
            acc2 = fmaf(v.z, w, acc2); acc3 = fmaf(v.w, w, acc3);
        } else {
            float2 v = *reinterpret_cast<const float2*>(x + (size_t)sw.x * D + c * 2);
            acc0 = fmaf(v.x, w, acc0); acc1 = fmaf(v.y, w, acc1);
        }
    }

    if (FUSE == 1) {
#pragma unroll
        for (int j = 0; j < VEC; ++j) {
            int col = c * VEC + j;
            float sv = g[col] * rsqrtf(rv[col] + EPS);
            float bb = b[col] * sv + (be[col] - rm[col] * sv);
            float* a = (j == 0) ? &acc0 : (j == 1) ? &acc1 : (j == 2) ? &acc2 : &acc3;
            *a = fmaxf(*a + bb, 0.0f);
        }
    }

    if (VEC == 4) {
        float4 o; o.x = acc0; o.y = acc1; o.z = acc2; o.w = acc3;
        *reinterpret_cast<float4*>(out + (size_t)nd * D + c * 4) = o;
    } else {
        float2 o; o.x = acc0; o.y = acc1;
        *reinterpret_cast<float2*>(out + (size_t)nd * D + c * 2) = o;
    }
}

// ---------------- register-tiled GEMM: out = epilogue(X @ W) ----------------
// MODE 0: z=(acc+b)*s+t, relu      (GCN layer, aggregate-first)
// MODE 1: z=acc*s                   (transform-first pre-aggregation)
// MODE 2: z=relu(acc+b)*s+t        (classifier Linear->ReLU->BN)
template<int K, int DOUT, int MODE>
__global__ __launch_bounds__(256) void gemm_tile(const float* __restrict__ X, const float* __restrict__ W,
                                                 const float* __restrict__ b, const float* __restrict__ g,
                                                 const float* __restrict__ be, const float* __restrict__ rm,
                                                 const float* __restrict__ rv, float* __restrict__ out, int n) {
    constexpr int TM = 8;
    constexpr int TN = (DOUT >= 64) ? 8 : 4;
    constexpr int BN = (DOUT < 128) ? DOUT : 128;
    constexpr int BM = 256 * TM * TN / BN;
    constexpr int KT = (K % 32 == 0) ? 32 : K;
    constexpr int NTN = BN / TN;            // col groups
    static_assert((BM / TM) * NTN == 256, "thread mapping");

    __shared__ float xs[BM][KT + 1];
    __shared__ float ws[KT][BN];

    const int tid = threadIdx.x;
    const int tn_idx = tid % NTN;
    const int tm_idx = tid / NTN;
    const int row0 = blockIdx.x * BM;
    const int col0 = blockIdx.y * BN;

    float acc[TM][TN];
#pragma unroll
    for (int i = 0; i < TM; ++i)
#pragma unroll
        for (int j = 0; j < TN; ++j) acc[i][j] = 0.0f;

    for (int k0 = 0; k0 < K; k0 += KT) {
        // stage X tile (row-major, pad +1)
        if (K % 4 == 0) {
            for (int i = tid; i < BM * KT / 4; i += 256) {
                int m = i / (KT / 4), kq = i - m * (KT / 4);
                int k = kq * 4;
                int rr = row0 + m;
                float4 v = (rr < n) ? *reinterpret_cast<const float4*>(X + (size_t)rr * K + k0 + k)
                                    : make_float4(0.f, 0.f, 0.f, 0.f);
                xs[m][k + 0] = v.x; xs[m][k + 1] = v.y; xs[m][k + 2] = v.z; xs[m][k + 3] = v.w;
            }
        } else {
            for (int i = tid; i < BM * KT / 2; i += 256) {
                int m = i / (KT / 2), kq = i - m * (KT / 2);
                int k = kq * 2;
                int rr = row0 + m;
                float2 v = (rr < n) ? *reinterpret_cast<const float2*>(X + (size_t)rr * K + k0 + k)
                                    : make_float2(0.f, 0.f);
                xs[m][k + 0] = v.x; xs[m][k + 1] = v.y;
            }
        }
        // stage W tile
        for (int i = tid; i < KT * BN / 4; i += 256) {
            int k = i / (BN / 4), cq = i - k * (BN / 4);
            float4 wv = *reinterpret_cast<const float4*>(W + (size_t)(k0 + k) * DOUT + col0 + cq * 4);
            *reinterpret_cast<float4*>(&ws[k][cq * 4]) = wv;
        }
        __syncthreads();

#pragma unroll 2
        for (int k = 0; k < KT; ++k) {
            float av[TM], bv[TN];
#pragma unroll
            for (int i = 0; i < TM; ++i) av[i] = xs[tm_idx * TM + i][k];
#pragma unroll
            for (int j = 0; j < TN; j += 4)
                *reinterpret_cast<float4*>(&bv[j]) = *reinterpret_cast<const float4*>(&ws[k][tn_idx * TN + j]);
#pragma unroll
            for (int i = 0; i < TM; ++i)
#pragma unroll
                for (int j = 0; j < TN; ++j)
                    acc[i][j] = fmaf(av[i], bv[j], acc[i][j]);
        }
        __syncthreads();
    }

    // epilogue params per column
    float s[TN], t[TN], bias[TN];
#pragma unroll
    for (int j = 0; j < TN; ++j) {
        int col = col0 + tn_idx * TN + j;
        if (MODE == 0 || MODE == 2) {
            float sv = g[col] * rsqrtf(rv[col] + EPS);
            s[j] = sv; t[j] = be[col] - rm[col] * sv; bias[j] = b[col];
        } else {
            s[j] = g[col] * rsqrtf(rv[col] + EPS); t[j] = 0.f; bias[j] = 0.f;
        }
    }

#pragma unroll
    for (int i = 0; i < TM; ++i) {
        int rr = row0 + tm_idx * TM + i;
        if (rr < n) {
            float o[TN];
#pragma unroll
            for (int j = 0; j < TN; ++j) {
                float z = acc[i][j];
                if (MODE == 0)      { z = (z + bias[j]) * s[j] + t[j]; z = fmaxf(z, 0.0f); }
                else if (MODE == 1) { z = z * s[j]; }
                else                { z = fmaxf(z + bias[j], 0.0f) * s[j] + t[j]; }
                o[j] = z;
            }
            float* op = out + (size_t)rr * DOUT + col0 + tn_idx * TN;
#pragma unroll
            for (int j = 0; j < TN; j += 4)
                *reinterpret_cast<float4*>(op + j) = *reinterpret_cast<const float4*>(&o[j]);
        }
    }
}

// final Linear 32 -> 2
__global__ __launch_bounds__(256) void final_linear(const float* __restrict__ X, const float* __restrict__ W,
                                                    const float* __restrict__ b, float* __restrict__ out, int n) {
    int row = blockIdx.x * 256 + threadIdx.x;
    if (row >= n) return;
    float a0 = 0.0f, a1 = 0.0f;
#pragma unroll
    for (int k = 0; k < 32; ++k) {
        float xv = X[(size_t)row * 32 + k];
        a0 = fmaf(xv, W[k * 2 + 0], a0);
        a1 = fmaf(xv, W[k * 2 + 1], a1);
    }
    out[(size_t)row * 2 + 0] = a0 + b[0];
    out[(size_t)row * 2 + 1] = a1 + b[1];
}

// ---------------- launch ----------------

extern "C" void kernel_launch(void* const* d_in, const int* in_sizes, int n_in,
                              void* d_out, int out_size, void* d_ws, size_t ws_size,
                              hipStream_t stream) {
    const float* x  = (const float*)d_in[0];
    const int*   ei = (const int*)d_in[1];
    const int E = in_sizes[1] / 2;
    const int n = in_sizes[0] / 42;
    const int* src = ei;
    const int* dst = ei + E;

    const float *W1 = (const float*)d_in[2],  *b1 = (const float*)d_in[3],  *g1 = (const float*)d_in[4],
                *be1 = (const float*)d_in[5], *rm1 = (const float*)d_in[6], *rv1 = (const float*)d_in[7];
    const float *W2 = (const float*)d_in[8],  *b2 = (const float*)d_in[9],  *g2 = (const float*)d_in[10],
                *be2 = (const float*)d_in[11], *rm2 = (const float*)d_in[12], *rv2 = (const float*)d_in[13];
    const float *W3 = (const float*)d_in[14], *b3 = (const float*)d_in[15], *g3 = (const float*)d_in[16],
                *be3 = (const float*)d_in[17], *rm3 = (const float*)d_in[18], *rv3 = (const float*)d_in[19];
    const float *W4 = (const float*)d_in[20], *b4 = (const float*)d_in[21], *g4 = (const float*)d_in[22],
                *be4 = (const float*)d_in[23], *rm4 = (const float*)d_in[24], *rv4 = (const float*)d_in[25];
    const float *cW1 = (const float*)d_in[26], *cb1 = (const float*)d_in[27], *cg1 = (const float*)d_in[28],
                *cbe1 = (const float*)d_in[29], *crm1 = (const float*)d_in[30], *crv1 = (const float*)d_in[31];
    const float *cW2 = (const float*)d_in[32], *cb2 = (const float*)d_in[33], *cg2 = (const float*)d_in[34],
                *cbe2 = (const float*)d_in[35], *crm2 = (const float*)d_in[36], *crv2 = (const float*)d_in[37];
    const float *cW3 = (const float*)d_in[38], *cb3 = (const float*)d_in[39];

    // ---- workspace layout ----
    int2*  csr    = (int2*)d_ws;                       // E
    float* bufA   = (float*)(csr + E);                 // n*128
    float* bufB   = bufA + (size_t)n * 128;            // n*256
    float* dis    = bufB + (size_t)n * 256;            // n
    int*   cnt    = (int*)(dis + n);                   // n
    int*   fill   = cnt + n;                           // n
    int*   rowptr = fill + n;                          // n+1
    int*   bsum   = rowptr + n + 1;                    // 256

    dim3 blk(256);
    auto nb = [](long total) { return dim3((unsigned)((total + 255) / 256)); };
    const int nscan = (n + 1023) / 1024;
    const float* nul = nullptr;

    // ---- CSR build ----
    hipMemsetAsync(cnt, 0, (size_t)2 * n * sizeof(int), stream);
    count_deg<<<nb(E), blk, 0, stream>>>(dst, cnt, E);
    calc_dis<<<nb(n), blk, 0, stream>>>(cnt, dis, n);
    scan1<<<dim3(nscan), blk, 0, stream>>>(cnt, rowptr, bsum, n);
    scan2<<<dim3(1), blk, 0, stream>>>(bsum, nscan);
    scan3<<<nb(n), blk, 0, stream>>>(rowptr, bsum, n, E);
    csr_fill<<<nb(E), blk, 0, stream>>>(src, dst, dis, rowptr, fill, csr, E);

    // ---- Layer 1 (aggregate-first, d=42)
    agg_gather<42, 2, 0><<<nb((long)n * 21), blk, 0, stream>>>(x, dis, rowptr, csr, nul, nul, nul, nul, nul, bufA, n);
    gemm_tile<42, 128, 0><<<dim3((n + 127) / 128, 1), blk, 0, stream>>>(bufA, W1, b1, g1, be1, rm1, rv1, bufB, n);

    // ---- Layer 2 (aggregate-first, d=128)
    agg_gather<128, 4, 0><<<nb((long)n * 32), blk, 0, stream>>>(bufB, dis, rowptr, csr, nul, nul, nul, nul, nul, bufA, n);
    gemm_tile<128, 256, 0><<<dim3((n + 127) / 128, 2), blk, 0, stream>>>(bufA, W2, b2, g2, be2, rm2, rv2, bufB, n);

    // ---- Layer 3 (transform-first): gemm 256->128 (scale s), agg + fused bias/bn/relu
    gemm_tile<256, 128, 1><<<dim3((n + 127) / 128, 1), blk, 0, stream>>>(bufB, W3, b3, g3, be3, rm3, rv3, bufA, n);
    agg_gather<128, 4, 1><<<nb((long)n * 32), blk, 0, stream>>>(bufA, dis, rowptr, csr, b3, g3, be3, rm3, rv3, bufB, n);

    // ---- Layer 4 (transform-first): gemm 128->64 (scale s), agg + fused bias/bn/relu
    gemm_tile<128, 64, 1><<<dim3((n + 255) / 256, 1), blk, 0, stream>>>(bufB, W4, b4, g4, be4, rm4, rv4, bufA, n);
    agg_gather<64, 4, 1><<<nb((long)n * 16), blk, 0, stream>>>(bufA, dis, rowptr, csr, b4, g4, be4, rm4, rv4, bufB, n);

    // ---- Classifier
    gemm_tile<64, 64, 2><<<dim3((n + 255) / 256, 1), blk, 0, stream>>>(bufB, cW1, cb1, cg1, cbe1, crm1, crv1, bufA, n);
    gemm_tile<64, 32, 2><<<dim3((n + 255) / 256, 1), blk, 0, stream>>>(bufA, cW2, cb2, cg2, cbe2, crm2, crv2, bufB, n);
    final_linear<<<nb(n), blk, 0, stream>>>(bufB, cW3, cb3, (float*)d_out, n);
}

// Round 4
// 711.435 us; speedup vs baseline: 11.2621x; 1.1892x over previous
//
#include <hip/hip_runtime.h>

#define EPS 1e-5f

typedef __attribute__((ext_vector_type(8))) short short8v;
typedef __attribute__((ext_vector_type(4))) float f32x4;

__device__ __forceinline__ unsigned short f2bf(float f) {
    union { float f; unsigned int u; } v; v.f = f;
    unsigned int r = v.u + 0x7fffu + ((v.u >> 16) & 1u);
    return (unsigned short)(r >> 16);
}
__device__ __forceinline__ float bf2f(unsigned short h) {
    union { unsigned int u; float f; } v; v.u = ((unsigned int)h) << 16;
    return v.f;
}

// ---------------- degree count ----------------

__global__ __launch_bounds__(256) void count_deg(const int* __restrict__ dst, int* __restrict__ cnt, int E) {
    int i = blockIdx.x * 256 + threadIdx.x;
    if (i < E) atomicAdd(&cnt[dst[i]], 1);
}

__global__ __launch_bounds__(256) void calc_dis(const int* __restrict__ cnt, float* __restrict__ dis, int n) {
    int i = blockIdx.x * 256 + threadIdx.x;
    if (i < n) dis[i] = rsqrtf((float)cnt[i] + 1.0f);
}

// ---------------- exclusive scan (3-kernel) ----------------
__global__ __launch_bounds__(256) void scan1(const int* __restrict__ cnt, int* __restrict__ excl,
                                             int* __restrict__ bsum, int n) {
    __shared__ int sdata[256];
    const int tid = threadIdx.x;
    const int base = blockIdx.x * 1024 + tid * 4;
    int v0 = (base + 0 < n) ? cnt[base + 0] : 0;
    int v1 = (base + 1 < n) ? cnt[base + 1] : 0;
    int v2 = (base + 2 < n) ? cnt[base + 2] : 0;
    int v3 = (base + 3 < n) ? cnt[base + 3] : 0;
    int s = v0 + v1 + v2 + v3;
    sdata[tid] = s;
    __syncthreads();
    for (int off = 1; off < 256; off <<= 1) {
        int t = (tid >= off) ? sdata[tid - off] : 0;
        __syncthreads();
        sdata[tid] += t;
        __syncthreads();
    }
    if (tid == 255) bsum[blockIdx.x] = sdata[255];
    int run = sdata[tid] - s;
    if (base + 0 < n) excl[base + 0] = run; run += v0;
    if (base + 1 < n) excl[base + 1] = run; run += v1;
    if (base + 2 < n) excl[base + 2] = run; run += v2;
    if (base + 3 < n) excl[base + 3] = run;
}

__global__ __launch_bounds__(256) void scan2(int* __restrict__ bsum, int nb) {
    __shared__ int sdata[256];
    const int tid = threadIdx.x;
    int v = (tid < nb) ? bsum[tid] : 0;
    sdata[tid] = v;
    __syncthreads();
    for (int off = 1; off < 256; off <<= 1) {
        int t = (tid >= off) ? sdata[tid - off] : 0;
        __syncthreads();
        sdata[tid] += t;
        __syncthreads();
    }
    if (tid < nb) bsum[tid] = sdata[tid] - v;
}

__global__ __launch_bounds__(256) void scan3(int* __restrict__ rowptr, const int* __restrict__ bsum, int n, int E) {
    int i = blockIdx.x * 256 + threadIdx.x;
    if (i < n) rowptr[i] += bsum[i >> 10];
    if (i == 0) rowptr[n] = E;
}

// ---------------- CSR fill ----------------
__global__ __launch_bounds__(256) void csr_fill(const int* __restrict__ src, const int* __restrict__ dst,
                                                const float* __restrict__ dis, const int* __restrict__ rowptr,
                                                int* __restrict__ fill, int2* __restrict__ csr, int E) {
    int e = blockIdx.x * 256 + threadIdx.x;
    if (e >= E) return;
    int s = src[e], d = dst[e];
    int pos = rowptr[d] + atomicAdd(&fill[d], 1);
    csr[pos] = make_int2(s, __float_as_int(dis[s] * dis[d]));
}

// ---------------- W split: [K][DOUT] f32 -> transposed bf16 hi/lo [DOUT][Kpad] ----------------
__global__ __launch_bounds__(256) void split_w(const float* __restrict__ W, unsigned short* __restrict__ hi,
                                               unsigned short* __restrict__ lo, int K, int DOUT, int Kpad) {
    int i = blockIdx.x * 256 + threadIdx.x;
    if (i >= DOUT * Kpad) return;
    int c = i / Kpad, k = i - c * Kpad;
    float w = (k < K) ? W[(size_t)k * DOUT + c] : 0.0f;
    unsigned short h = f2bf(w);
    hi[i] = h;
    lo[i] = f2bf(w - bf2f(h));
}

// ---------------- aggregation (gather), 4-deep unrolled ----------------
// FUSE 0: out = A_norm @ x
// FUSE 1: out = relu(A_norm @ x + (b*s + t))
template<int D, int VEC, int FUSE>
__global__ __launch_bounds__(256) void agg_gather(const float* __restrict__ x, const float* __restrict__ dis,
                                                  const int* __restrict__ rowptr, const int2* __restrict__ csr,
                                                  const float* __restrict__ b, const float* __restrict__ g,
                                                  const float* __restrict__ be, const float* __restrict__ rm,
                                                  const float* __restrict__ rv,
                                                  float* __restrict__ out, int n) {
    constexpr int CPE = D / VEC;
    int gid = blockIdx.x * 256 + threadIdx.x;
    int nd = gid / CPE, c = gid - nd * CPE;
    if (nd >= n) return;
    float dd = dis[nd]; dd *= dd;

    float acc0, acc1, acc2, acc3;
    if (VEC == 4) {
        float4 v = *reinterpret_cast<const float4*>(x + (size_t)nd * D + c * 4);
        acc0 = v.x * dd; acc1 = v.y * dd; acc2 = v.z * dd; acc3 = v.w * dd;
    } else {
        float2 v = *reinterpret_cast<const float2*>(x + (size_t)nd * D + c * 2);
        acc0 = v.x * dd; acc1 = v.y * dd; acc2 = 0.0f; acc3 = 0.0f;
    }

    const int r0 = rowptr[nd], r1 = rowptr[nd + 1];
    int i = r0;
    for (; i + 4 <= r1; i += 4) {
        int2 s0 = csr[i + 0], s1 = csr[i + 1], s2 = csr[i + 2], s3 = csr[i + 3];
        float w0 = __int_as_float(s0.y), w1 = __int_as_float(s1.y);
        float w2 = __int_as_float(s2.y), w3 = __int_as_float(s3.y);
        if (VEC == 4) {
            float4 v0 = *reinterpret_cast<const float4*>(x + (size_t)s0.x * D + c * 4);
            float4 v1 = *reinterpret_cast<const float4*>(x + (size_t)s1.x * D + c * 4);
            float4 v2 = *reinterpret_cast<const float4*>(x + (size_t)s2.x * D + c * 4);
            float4 v3 = *reinterpret_cast<const float4*>(x + (size_t)s3.x * D + c * 4);
            acc0 = fmaf(v0.x, w0, acc0); acc1 = fmaf(v0.y, w0, acc1); acc2 = fmaf(v0.z, w0, acc2); acc3 = fmaf(v0.w, w0, acc3);
            acc0 = fmaf(v1.x, w1, acc0); acc1 = fmaf(v1.y, w1, acc1); acc2 = fmaf(v1.z, w1, acc2); acc3 = fmaf(v1.w, w1, acc3);
            acc0 = fmaf(v2.x, w2, acc0); acc1 = fmaf(v2.y, w2, acc1); acc2 = fmaf(v2.z, w2, acc2); acc3 = fmaf(v2.w, w2, acc3);
            acc0 = fmaf(v3.x, w3, acc0); acc1 = fmaf(v3.y, w3, acc1); acc2 = fmaf(v3.z, w3, acc2); acc3 = fmaf(v3.w, w3, acc3);
        } else {
            float2 v0 = *reinterpret_cast<const float2*>(x + (size_t)s0.x * D + c * 2);
            float2 v1 = *reinterpret_cast<const float2*>(x + (size_t)s1.x * D + c * 2);
            float2 v2 = *reinterpret_cast<const float2*>(x + (size_t)s2.x * D + c * 2);
            float2 v3 = *reinterpret_cast<const float2*>(x + (size_t)s3.x * D + c * 2);
            acc0 = fmaf(v0.x, w0, acc0); acc1 = fmaf(v0.y, w0, acc1);
            acc0 = fmaf(v1.x, w1, acc0); acc1 = fmaf(v1.y, w1, acc1);
            acc0 = fmaf(v2.x, w2, acc0); acc1 = fmaf(v2.y, w2, acc1);
            acc0 = fmaf(v3.x, w3, acc0); acc1 = fmaf(v3.y, w3, acc1);
        }
    }
    for (; i < r1; ++i) {
        int2 sw = csr[i];
        float w = __int_as_float(sw.y);
        if (VEC == 4) {
            float4 v = *reinterpret_cast<const float4*>(x + (size_t)sw.x * D + c * 4);
            acc0 = fmaf(v.x, w, acc0); acc1 = fmaf(v.y, w, acc1);
            acc2 = fmaf(v.z, w, acc2); acc3 = fmaf(v.w, w, acc3);
        } else {
            float2 v = *reinterpret_cast<const float2*>(x + (size_t)sw.x * D + c * 2);
            acc0 = fmaf(v.x, w, acc0); acc1 = fmaf(v.y, w, acc1);
        }
    }

    if (FUSE == 1) {
#pragma unroll
        for (int j = 0; j < VEC; ++j) {
            int col = c * VEC + j;
            float sv = g[col] * rsqrtf(rv[col] + EPS);
            float bb = b[col] * sv + (be[col] - rm[col] * sv);
            float* a = (j == 0) ? &acc0 : (j == 1) ? &acc1 : (j == 2) ? &acc2 : &acc3;
            *a = fmaxf(*a + bb, 0.0f);
        }
    }

    if (VEC == 4) {
        float4 o; o.x = acc0; o.y = acc1; o.z = acc2; o.w = acc3;
        *reinterpret_cast<float4*>(out + (size_t)nd * D + c * 4) = o;
    } else {
        float2 o; o.x = acc0; o.y = acc1;
        *reinterpret_cast<float2*>(out + (size_t)nd * D + c * 2) = o;
    }
}

// ---------------- split-bf16 MFMA GEMM: out = epilogue(X @ W) ----------------
// X: f32 [n][K] (K % 32 == 0). Wh/Wl: bf16 [DOUT][K] (transposed, pre-split).
// block = 256 thr = 4 waves; 64 rows/block, BN=min(DOUT,128) cols (grid.y tiles).
// MODE 0: z=(acc+b)*s+t, relu ; MODE 1: z=acc*s ; MODE 2: z=relu(acc+b)*s+t
template<int K, int DOUT, int MODE>
__global__ __launch_bounds__(256) void gemm_mfma(const float* __restrict__ X,
                                                 const unsigned short* __restrict__ Wh,
                                                 const unsigned short* __restrict__ Wl,
                                                 const float* __restrict__ b, const float* __restrict__ g,
                                                 const float* __restrict__ be, const float* __restrict__ rm,
                                                 const float* __restrict__ rv, float* __restrict__ out, int n) {
    constexpr int BN = (DOUT < 128) ? DOUT : 128;
    constexpr int NT = BN / 16;
    constexpr int KSTEPS = K / 32;
    constexpr int LDA = 40;                     // ushort stride: 80 B (16B-aligned frags, low conflict)
    __shared__ unsigned short xh[64][LDA], xl[64][LDA];
    __shared__ unsigned short wh[BN][LDA], wl[BN][LDA];

    const int tid = threadIdx.x;
    const int wave = tid >> 6, lane = tid & 63;
    const int row0 = blockIdx.x * 64;
    const int col0 = blockIdx.y * BN;
    const int r_l = lane & 15;
    const int k_l = (lane >> 4) * 8;

    f32x4 acc[NT];
#pragma unroll
    for (int t = 0; t < NT; ++t) acc[t] = (f32x4){0.f, 0.f, 0.f, 0.f};

    for (int ks = 0; ks < KSTEPS; ++ks) {
        const int k0 = ks * 32;
        // stage X (f32 -> split bf16): 64 rows x 32 k
        for (int i = tid; i < 64 * 8; i += 256) {
            int m = i >> 3, q = i & 7;
            int rr = row0 + m;
            float4 v = (rr < n) ? *reinterpret_cast<const float4*>(X + (size_t)rr * K + k0 + q * 4)
                                : make_float4(0.f, 0.f, 0.f, 0.f);
            unsigned short h0 = f2bf(v.x), h1 = f2bf(v.y), h2 = f2bf(v.z), h3 = f2bf(v.w);
            unsigned short l0 = f2bf(v.x - bf2f(h0)), l1 = f2bf(v.y - bf2f(h1));
            unsigned short l2 = f2bf(v.z - bf2f(h2)), l3 = f2bf(v.w - bf2f(h3));
            uint2 ph = make_uint2((unsigned)h0 | ((unsigned)h1 << 16), (unsigned)h2 | ((unsigned)h3 << 16));
            uint2 pl = make_uint2((unsigned)l0 | ((unsigned)l1 << 16), (unsigned)l2 | ((unsigned)l3 << 16));
            *reinterpret_cast<uint2*>(&xh[m][q * 4]) = ph;
            *reinterpret_cast<uint2*>(&xl[m][q * 4]) = pl;
        }
        // stage Wt tiles: BN rows x 32 k (16B chunks)
        for (int i = tid; i < BN * 4; i += 256) {
            int cc = i >> 2, q = i & 3;
            size_t goff = (size_t)(col0 + cc) * K + k0 + q * 8;
            *reinterpret_cast<uint4*>(&wh[cc][q * 8]) = *reinterpret_cast<const uint4*>(Wh + goff);
            *reinterpret_cast<uint4*>(&wl[cc][q * 8]) = *reinterpret_cast<const uint4*>(Wl + goff);
        }
        __syncthreads();

        short8v ah = *reinterpret_cast<const short8v*>(&xh[wave * 16 + r_l][k_l]);
        short8v al = *reinterpret_cast<const short8v*>(&xl[wave * 16 + r_l][k_l]);
#pragma unroll
        for (int t = 0; t < NT; ++t) {
            short8v bh = *reinterpret_cast<const short8v*>(&wh[t * 16 + r_l][k_l]);
            short8v bl = *reinterpret_cast<const short8v*>(&wl[t * 16 + r_l][k_l]);
            acc[t] = __builtin_amdgcn_mfma_f32_16x16x32_bf16(ah, bh, acc[t], 0, 0, 0);
            acc[t] = __builtin_amdgcn_mfma_f32_16x16x32_bf16(al, bh, acc[t], 0, 0, 0);
            acc[t] = __builtin_amdgcn_mfma_f32_16x16x32_bf16(ah, bl, acc[t], 0, 0, 0);
        }
        __syncthreads();
    }

    // epilogue + store: lane covers rows (lane>>4)*4+r of its wave's 16-row block, col = t*16 + (lane&15)
    const int orow = row0 + wave * 16 + (lane >> 4) * 4;
#pragma unroll
    for (int t = 0; t < NT; ++t) {
        int col = col0 + t * 16 + r_l;
        float s, tt, bias;
        if (MODE == 0 || MODE == 2) {
            float sv = g[col] * rsqrtf(rv[col] + EPS);
            s = sv; tt = be[col] - rm[col] * sv; bias = b[col];
        } else {
            s = g[col] * rsqrtf(rv[col] + EPS); tt = 0.f; bias = 0.f;
        }
#pragma unroll
        for (int r = 0; r < 4; ++r) {
            int rr = orow + r;
            if (rr < n) {
                float z = acc[t][r];
                if (MODE == 0)      { z = (z + bias) * s + tt; z = fmaxf(z, 0.0f); }
                else if (MODE == 1) { z = z * s; }
                else                { z = fmaxf(z + bias, 0.0f) * s + tt; }
                out[(size_t)rr * DOUT + col] = z;
            }
        }
    }
}

// ---------------- f32 register-tiled GEMM (layer-1 + classifier) ----------------
template<int K, int DOUT, int MODE>
__global__ __launch_bounds__(256) void gemm_tile(const float* __restrict__ X, const float* __restrict__ W,
                                                 const float* __restrict__ b, const float* __restrict__ g,
                                                 const float* __restrict__ be, const float* __restrict__ rm,
                                                 const float* __restrict__ rv, float* __restrict__ out, int n) {
    constexpr int TM = 8;
    constexpr int TN = (DOUT >= 64) ? 8 : 4;
    constexpr int BN = (DOUT < 128) ? DOUT : 128;
    constexpr int BM = 256 * TM * TN / BN;
    constexpr int KT = (K % 32 == 0) ? 32 : K;
    constexpr int NTN = BN / TN;
    static_assert((BM / TM) * NTN == 256, "thread mapping");

    __shared__ float xs[BM][KT + 1];
    __shared__ float ws[KT][BN];

    const int tid = threadIdx.x;
    const int tn_idx = tid % NTN;
    const int tm_idx = tid / NTN;
    const int row0 = blockIdx.x * BM;
    const int col0 = blockIdx.y * BN;

    float acc[TM][TN];
#pragma unroll
    for (int i = 0; i < TM; ++i)
#pragma unroll
        for (int j = 0; j < TN; ++j) acc[i][j] = 0.0f;

    for (int k0 = 0; k0 < K; k0 += KT) {
        if (K % 4 == 0) {
            for (int i = tid; i < BM * KT / 4; i += 256) {
                int m = i / (KT / 4), kq = i - m * (KT / 4);
                int k = kq * 4;
                int rr = row0 + m;
                float4 v = (rr < n) ? *reinterpret_cast<const float4*>(X + (size_t)rr * K + k0 + k)
                                    : make_float4(0.f, 0.f, 0.f, 0.f);
                xs[m][k + 0] = v.x; xs[m][k + 1] = v.y; xs[m][k + 2] = v.z; xs[m][k + 3] = v.w;
            }
        } else {
            for (int i = tid; i < BM * KT / 2; i += 256) {
                int m = i / (KT / 2), kq = i - m * (KT / 2);
                int k = kq * 2;
                int rr = row0 + m;
                float2 v = (rr < n) ? *reinterpret_cast<const float2*>(X + (size_t)rr * K + k0 + k)
                                    : make_float2(0.f, 0.f);
                xs[m][k + 0] = v.x; xs[m][k + 1] = v.y;
            }
        }
        for (int i = tid; i < KT * BN / 4; i += 256) {
            int k = i / (BN / 4), cq = i - k * (BN / 4);
            float4 wv = *reinterpret_cast<const float4*>(W + (size_t)(k0 + k) * DOUT + col0 + cq * 4);
            *reinterpret_cast<float4*>(&ws[k][cq * 4]) = wv;
        }
        __syncthreads();

#pragma unroll 2
        for (int k = 0; k < KT; ++k) {
            float av[TM], bv[TN];
#pragma unroll
            for (int i = 0; i < TM; ++i) av[i] = xs[tm_idx * TM + i][k];
#pragma unroll
            for (int j = 0; j < TN; j += 4)
                *reinterpret_cast<float4*>(&bv[j]) = *reinterpret_cast<const float4*>(&ws[k][tn_idx * TN + j]);
#pragma unroll
            for (int i = 0; i < TM; ++i)
#pragma unroll
                for (int j = 0; j < TN; ++j)
                    acc[i][j] = fmaf(av[i], bv[j], acc[i][j]);
        }
        __syncthreads();
    }

    float s[TN], t[TN], bias[TN];
#pragma unroll
    for (int j = 0; j < TN; ++j) {
        int col = col0 + tn_idx * TN + j;
        if (MODE == 0 || MODE == 2) {
            float sv = g[col] * rsqrtf(rv[col] + EPS);
            s[j] = sv; t[j] = be[col] - rm[col] * sv; bias[j] = b[col];
        } else {
            s[j] = g[col] * rsqrtf(rv[col] + EPS); t[j] = 0.f; bias[j] = 0.f;
        }
    }

#pragma unroll
    for (int i = 0; i < TM; ++i) {
        int rr = row0 + tm_idx * TM + i;
        if (rr < n) {
            float o[TN];
#pragma unroll
            for (int j = 0; j < TN; ++j) {
                float z = acc[i][j];
                if (MODE == 0)      { z = (z + bias[j]) * s[j] + t[j]; z = fmaxf(z, 0.0f); }
                else if (MODE == 1) { z = z * s[j]; }
                else                { z = fmaxf(z + bias[j], 0.0f) * s[j] + t[j]; }
                o[j] = z;
            }
            float* op = out + (size_t)rr * DOUT + col0 + tn_idx * TN;
#pragma unroll
            for (int j = 0; j < TN; j += 4)
                *reinterpret_cast<float4*>(op + j) = *reinterpret_cast<const float4*>(&o[j]);
        }
    }
}

// final Linear 32 -> 2
__global__ __launch_bounds__(256) void final_linear(const float* __restrict__ X, const float* __restrict__ W,
                                                    const float* __restrict__ b, float* __restrict__ out, int n) {
    int row = blockIdx.x * 256 + threadIdx.x;
    if (row >= n) return;
    float a0 = 0.0f, a1 = 0.0f;
#pragma unroll
    for (int k = 0; k < 32; ++k) {
        float xv = X[(size_t)row * 32 + k];
        a0 = fmaf(xv, W[k * 2 + 0], a0);
        a1 = fmaf(xv, W[k * 2 + 1], a1);
    }
    out[(size_t)row * 2 + 0] = a0 + b[0];
    out[(size_t)row * 2 + 1] = a1 + b[1];
}

// ---------------- launch ----------------

extern "C" void kernel_launch(void* const* d_in, const int* in_sizes, int n_in,
                              void* d_out, int out_size, void* d_ws, size_t ws_size,
                              hipStream_t stream) {
    const float* x  = (const float*)d_in[0];
    const int*   ei = (const int*)d_in[1];
    const int E = in_sizes[1] / 2;
    const int n = in_sizes[0] / 42;
    const int* src = ei;
    const int* dst = ei + E;

    const float *W1 = (const float*)d_in[2],  *b1 = (const float*)d_in[3],  *g1 = (const float*)d_in[4],
                *be1 = (const float*)d_in[5], *rm1 = (const float*)d_in[6], *rv1 = (const float*)d_in[7];
    const float *W2 = (const float*)d_in[8],  *b2 = (const float*)d_in[9],  *g2 = (const float*)d_in[10],
                *be2 = (const float*)d_in[11], *rm2 = (const float*)d_in[12], *rv2 = (const float*)d_in[13];
    const float *W3 = (const float*)d_in[14], *b3 = (const float*)d_in[15], *g3 = (const float*)d_in[16],
                *be3 = (const float*)d_in[17], *rm3 = (const float*)d_in[18], *rv3 = (const float*)d_in[19];
    const float *W4 = (const float*)d_in[20], *b4 = (const float*)d_in[21], *g4 = (const float*)d_in[22],
                *be4 = (const float*)d_in[23], *rm4 = (const float*)d_in[24], *rv4 = (const float*)d_in[25];
    const float *cW1 = (const float*)d_in[26], *cb1 = (const float*)d_in[27], *cg1 = (const float*)d_in[28],
                *cbe1 = (const float*)d_in[29], *crm1 = (const float*)d_in[30], *crv1 = (const float*)d_in[31];
    const float *cW2 = (const float*)d_in[32], *cb2 = (const float*)d_in[33], *cg2 = (const float*)d_in[34],
                *cbe2 = (const float*)d_in[35], *crm2 = (const float*)d_in[36], *crv2 = (const float*)d_in[37];
    const float *cW3 = (const float*)d_in[38], *cb3 = (const float*)d_in[39];

    // ---- workspace layout ----
    int2*  csr    = (int2*)d_ws;                        // E
    float* bufA   = (float*)(csr + E);                  // n*128
    float* bufB   = bufA + (size_t)n * 128;             // n*256
    float* dis    = bufB + (size_t)n * 256;             // n
    int*   cnt    = (int*)(dis + n);                    // n
    int*   fill   = cnt + n;                            // n
    int*   rowptr = fill + n;                           // n+1
    int*   bsum   = rowptr + n + 1;                     // 256
    unsigned short* w2h = (unsigned short*)(bsum + 256);  // 256*128
    unsigned short* w2l = w2h + 256 * 128;
    unsigned short* w3h = w2l + 256 * 128;                // 128*256
    unsigned short* w3l = w3h + 128 * 256;
    unsigned short* w4h = w3l + 128 * 256;                // 64*128
    unsigned short* w4l = w4h + 64 * 128;

    dim3 blk(256);
    auto nb = [](long total) { return dim3((unsigned)((total + 255) / 256)); };
    const int nscan = (n + 1023) / 1024;
    const float* nul = nullptr;

    // ---- CSR build + W splits ----
    hipMemsetAsync(cnt, 0, (size_t)2 * n * sizeof(int), stream);
    count_deg<<<nb(E), blk, 0, stream>>>(dst, cnt, E);
    calc_dis<<<nb(n), blk, 0, stream>>>(cnt, dis, n);
    scan1<<<dim3(nscan), blk, 0, stream>>>(cnt, rowptr, bsum, n);
    scan2<<<dim3(1), blk, 0, stream>>>(bsum, nscan);
    scan3<<<nb(n), blk, 0, stream>>>(rowptr, bsum, n, E);
    csr_fill<<<nb(E), blk, 0, stream>>>(src, dst, dis, rowptr, fill, csr, E);
    split_w<<<nb(256 * 128), blk, 0, stream>>>(W2, w2h, w2l, 128, 256, 128);
    split_w<<<nb(128 * 256), blk, 0, stream>>>(W3, w3h, w3l, 256, 128, 256);
    split_w<<<nb(64 * 128),  blk, 0, stream>>>(W4, w4h, w4l, 128, 64, 128);

    // ---- Layer 1 (aggregate-first, d=42)
    agg_gather<42, 2, 0><<<nb((long)n * 21), blk, 0, stream>>>(x, dis, rowptr, csr, nul, nul, nul, nul, nul, bufA, n);
    gemm_tile<42, 128, 0><<<dim3((n + 127) / 128, 1), blk, 0, stream>>>(bufA, W1, b1, g1, be1, rm1, rv1, bufB, n);

    // ---- Layer 2 (aggregate-first, d=128)
    agg_gather<128, 4, 0><<<nb((long)n * 32), blk, 0, stream>>>(bufB, dis, rowptr, csr, nul, nul, nul, nul, nul, bufA, n);
    gemm_mfma<128, 256, 0><<<dim3((n + 63) / 64, 2), blk, 0, stream>>>(bufA, w2h, w2l, b2, g2, be2, rm2, rv2, bufB, n);

    // ---- Layer 3 (transform-first): gemm 256->128 (scale s), agg + fused bias/bn/relu
    gemm_mfma<256, 128, 1><<<dim3((n + 63) / 64, 1), blk, 0, stream>>>(bufB, w3h, w3l, b3, g3, be3, rm3, rv3, bufA, n);
    agg_gather<128, 4, 1><<<nb((long)n * 32), blk, 0, stream>>>(bufA, dis, rowptr, csr, b3, g3, be3, rm3, rv3, bufB, n);

    // ---- Layer 4 (transform-first): gemm 128->64 (scale s), agg + fused bias/bn/relu
    gemm_mfma<128, 64, 1><<<dim3((n + 63) / 64, 1), blk, 0, stream>>>(bufB, w4h, w4l, b4, g4, be4, rm4, rv4, bufA, n);
    agg_gather<64, 4, 1><<<nb((long)n * 16), blk, 0, stream>>>(bufA, dis, rowptr, csr, b4, g4, be4, rm4, rv4, bufB, n);

    // ---- Classifier
    gemm_tile<64, 64, 2><<<dim3((n + 255) / 256, 1), blk, 0, stream>>>(bufB, cW1, cb1, cg1, cbe1, crm1, crv1, bufA, n);
    gemm_tile<64, 32, 2><<<dim3((n + 255) / 256, 1), blk, 0, stream>>>(bufA, cW2, cb2, cg2, cbe2, crm2, crv2, bufB, n);
    final_linear<<<nb(n), blk, 0, stream>>>(bufB, cW3, cb3, (float*)d_out, n);
}

// Round 5
// 587.166 us; speedup vs baseline: 13.6457x; 1.2116x over previous
//
#include <hip/hip_runtime.h>

#define EPS 1e-5f

typedef __attribute__((ext_vector_type(8))) short short8v;
typedef __attribute__((ext_vector_type(4))) float f32x4;

__device__ __forceinline__ unsigned short f2bf(float f) {
    union { float f; unsigned int u; } v; v.f = f;
    unsigned int r = v.u + 0x7fffu + ((v.u >> 16) & 1u);
    return (unsigned short)(r >> 16);
}
__device__ __forceinline__ float bf2f(unsigned short h) {
    union { unsigned int u; float f; } v; v.u = ((unsigned int)h) << 16;
    return v.f;
}

// ---------------- degree count ----------------

__global__ __launch_bounds__(256) void count_deg(const int* __restrict__ dst, int* __restrict__ cnt, int E) {
    int i = blockIdx.x * 256 + threadIdx.x;
    if (i < E) atomicAdd(&cnt[dst[i]], 1);
}

__global__ __launch_bounds__(256) void calc_dis(const int* __restrict__ cnt, float* __restrict__ dis, int n) {
    int i = blockIdx.x * 256 + threadIdx.x;
    if (i < n) dis[i] = rsqrtf((float)cnt[i] + 1.0f);
}

// ---------------- exclusive scan (3-kernel) ----------------
__global__ __launch_bounds__(256) void scan1(const int* __restrict__ cnt, int* __restrict__ excl,
                                             int* __restrict__ bsum, int n) {
    __shared__ int sdata[256];
    const int tid = threadIdx.x;
    const int base = blockIdx.x * 1024 + tid * 4;
    int v0 = (base + 0 < n) ? cnt[base + 0] : 0;
    int v1 = (base + 1 < n) ? cnt[base + 1] : 0;
    int v2 = (base + 2 < n) ? cnt[base + 2] : 0;
    int v3 = (base + 3 < n) ? cnt[base + 3] : 0;
    int s = v0 + v1 + v2 + v3;
    sdata[tid] = s;
    __syncthreads();
    for (int off = 1; off < 256; off <<= 1) {
        int t = (tid >= off) ? sdata[tid - off] : 0;
        __syncthreads();
        sdata[tid] += t;
        __syncthreads();
    }
    if (tid == 255) bsum[blockIdx.x] = sdata[255];
    int run = sdata[tid] - s;
    if (base + 0 < n) excl[base + 0] = run; run += v0;
    if (base + 1 < n) excl[base + 1] = run; run += v1;
    if (base + 2 < n) excl[base + 2] = run; run += v2;
    if (base + 3 < n) excl[base + 3] = run;
}

__global__ __launch_bounds__(256) void scan2(int* __restrict__ bsum, int nb) {
    __shared__ int sdata[256];
    const int tid = threadIdx.x;
    int v = (tid < nb) ? bsum[tid] : 0;
    sdata[tid] = v;
    __syncthreads();
    for (int off = 1; off < 256; off <<= 1) {
        int t = (tid >= off) ? sdata[tid - off] : 0;
        __syncthreads();
        sdata[tid] += t;
        __syncthreads();
    }
    if (tid < nb) bsum[tid] = sdata[tid] - v;
}

__global__ __launch_bounds__(256) void scan3(int* __restrict__ rowptr, const int* __restrict__ bsum, int n, int E) {
    int i = blockIdx.x * 256 + threadIdx.x;
    if (i < n) rowptr[i] += bsum[i >> 10];
    if (i == 0) rowptr[n] = E;
}

// ---------------- CSR fill ----------------
__global__ __launch_bounds__(256) void csr_fill(const int* __restrict__ src, const int* __restrict__ dst,
                                                const float* __restrict__ dis, const int* __restrict__ rowptr,
                                                int* __restrict__ fill, int2* __restrict__ csr, int E) {
    int e = blockIdx.x * 256 + threadIdx.x;
    if (e >= E) return;
    int s = src[e], d = dst[e];
    int pos = rowptr[d] + atomicAdd(&fill[d], 1);
    csr[pos] = make_int2(s, __float_as_int(dis[s] * dis[d]));
}

// ---------------- W split: [K][DOUT] f32 -> transposed bf16 hi/lo [DOUT][Kpad] ----------------
__global__ __launch_bounds__(256) void split_w(const float* __restrict__ W, unsigned short* __restrict__ hi,
                                               unsigned short* __restrict__ lo, int K, int DOUT, int Kpad) {
    int i = blockIdx.x * 256 + threadIdx.x;
    if (i >= DOUT * Kpad) return;
    int c = i / Kpad, k = i - c * Kpad;
    float w = (k < K) ? W[(size_t)k * DOUT + c] : 0.0f;
    unsigned short h = f2bf(w);
    hi[i] = h;
    lo[i] = f2bf(w - bf2f(h));
}

// ---------------- f32 aggregation (layer 1 only, D=42) ----------------
template<int D, int VEC, int FUSE>
__global__ __launch_bounds__(256) void agg_gather(const float* __restrict__ x, const float* __restrict__ dis,
                                                  const int* __restrict__ rowptr, const int2* __restrict__ csr,
                                                  const float* __restrict__ b, const float* __restrict__ g,
                                                  const float* __restrict__ be, const float* __restrict__ rm,
                                                  const float* __restrict__ rv,
                                                  float* __restrict__ out, int n) {
    constexpr int CPE = D / VEC;
    int gid = blockIdx.x * 256 + threadIdx.x;
    int nd = gid / CPE, c = gid - nd * CPE;
    if (nd >= n) return;
    float dd = dis[nd]; dd *= dd;

    float acc0, acc1;
    {
        float2 v = *reinterpret_cast<const float2*>(x + (size_t)nd * D + c * 2);
        acc0 = v.x * dd; acc1 = v.y * dd;
    }
    const int r0 = rowptr[nd], r1 = rowptr[nd + 1];
    int i = r0;
    for (; i + 2 <= r1; i += 2) {
        int2 s0 = csr[i], s1 = csr[i + 1];
        float w0 = __int_as_float(s0.y), w1 = __int_as_float(s1.y);
        float2 v0 = *reinterpret_cast<const float2*>(x + (size_t)s0.x * D + c * 2);
        float2 v1 = *reinterpret_cast<const float2*>(x + (size_t)s1.x * D + c * 2);
        acc0 = fmaf(v0.x, w0, acc0); acc1 = fmaf(v0.y, w0, acc1);
        acc0 = fmaf(v1.x, w1, acc0); acc1 = fmaf(v1.y, w1, acc1);
    }
    for (; i < r1; ++i) {
        int2 sw = csr[i];
        float w = __int_as_float(sw.y);
        float2 v = *reinterpret_cast<const float2*>(x + (size_t)sw.x * D + c * 2);
        acc0 = fmaf(v.x, w, acc0); acc1 = fmaf(v.y, w, acc1);
    }
    float2 o; o.x = acc0; o.y = acc1;
    *reinterpret_cast<float2*>(out + (size_t)nd * D + c * 2) = o;
}

// ---------------- bf16 aggregation (gather 8 elems / 16B per lane) ----------------
// FUSE 0: out = A_norm @ x ; FUSE 1: out = relu(A_norm @ x + (b*s+t))
template<int D, int FUSE>
__global__ __launch_bounds__(256) void agg_bf(const unsigned short* __restrict__ x, const float* __restrict__ dis,
                                              const int* __restrict__ rowptr, const int2* __restrict__ csr,
                                              const float* __restrict__ b, const float* __restrict__ g,
                                              const float* __restrict__ be, const float* __restrict__ rm,
                                              const float* __restrict__ rv,
                                              float* __restrict__ out, int n) {
    constexpr int CPE = D / 8;
    int gid = blockIdx.x * 256 + threadIdx.x;
    int nd = gid / CPE, c = gid - nd * CPE;
    if (nd >= n) return;
    float dd = dis[nd]; dd *= dd;

    float acc[8];
    {
        short8v v = *reinterpret_cast<const short8v*>(x + (size_t)nd * D + c * 8);
#pragma unroll
        for (int j = 0; j < 8; ++j) acc[j] = bf2f((unsigned short)v[j]) * dd;
    }
    const int r0 = rowptr[nd], r1 = rowptr[nd + 1];
    int i = r0;
    for (; i + 2 <= r1; i += 2) {
        int2 s0 = csr[i], s1 = csr[i + 1];
        float w0 = __int_as_float(s0.y), w1 = __int_as_float(s1.y);
        short8v v0 = *reinterpret_cast<const short8v*>(x + (size_t)s0.x * D + c * 8);
        short8v v1 = *reinterpret_cast<const short8v*>(x + (size_t)s1.x * D + c * 8);
#pragma unroll
        for (int j = 0; j < 8; ++j) acc[j] = fmaf(bf2f((unsigned short)v0[j]), w0, acc[j]);
#pragma unroll
        for (int j = 0; j < 8; ++j) acc[j] = fmaf(bf2f((unsigned short)v1[j]), w1, acc[j]);
    }
    for (; i < r1; ++i) {
        int2 sw = csr[i];
        float w = __int_as_float(sw.y);
        short8v v = *reinterpret_cast<const short8v*>(x + (size_t)sw.x * D + c * 8);
#pragma unroll
        for (int j = 0; j < 8; ++j) acc[j] = fmaf(bf2f((unsigned short)v[j]), w, acc[j]);
    }

    if (FUSE == 1) {
#pragma unroll
        for (int j = 0; j < 8; ++j) {
            int col = c * 8 + j;
            float sv = g[col] * rsqrtf(rv[col] + EPS);
            float bb = b[col] * sv + (be[col] - rm[col] * sv);
            acc[j] = fmaxf(acc[j] + bb, 0.0f);
        }
    }

    float4 o0, o1;
    o0.x = acc[0]; o0.y = acc[1]; o0.z = acc[2]; o0.w = acc[3];
    o1.x = acc[4]; o1.y = acc[5]; o1.z = acc[6]; o1.w = acc[7];
    float* op = out + (size_t)nd * D + c * 8;
    *reinterpret_cast<float4*>(op) = o0;
    *reinterpret_cast<float4*>(op + 4) = o1;
}

// ---------------- split-bf16 MFMA GEMM ----------------
// MODE 0: z=(acc+b)*s+t, relu ; MODE 1: z=acc*s ; MODE 2: z=relu(acc+b)*s+t
// OUTBF: 1 -> write bf16 (ushort), 0 -> f32
template<int K, int DOUT, int MODE, int OUTBF>
__global__ __launch_bounds__(256) void gemm_mfma(const float* __restrict__ X,
                                                 const unsigned short* __restrict__ Wh,
                                                 const unsigned short* __restrict__ Wl,
                                                 const float* __restrict__ b, const float* __restrict__ g,
                                                 const float* __restrict__ be, const float* __restrict__ rm,
                                                 const float* __restrict__ rv, void* __restrict__ outv, int n) {
    constexpr int BN = (DOUT < 128) ? DOUT : 128;
    constexpr int NT = BN / 16;
    constexpr int KSTEPS = K / 32;
    constexpr int LDA = 40;
    __shared__ unsigned short xh[64][LDA], xl[64][LDA];
    __shared__ unsigned short wh[BN][LDA], wl[BN][LDA];

    const int tid = threadIdx.x;
    const int wave = tid >> 6, lane = tid & 63;
    const int row0 = blockIdx.x * 64;
    const int col0 = blockIdx.y * BN;
    const int r_l = lane & 15;
    const int k_l = (lane >> 4) * 8;

    f32x4 acc[NT];
#pragma unroll
    for (int t = 0; t < NT; ++t) acc[t] = (f32x4){0.f, 0.f, 0.f, 0.f};

    for (int ks = 0; ks < KSTEPS; ++ks) {
        const int k0 = ks * 32;
        for (int i = tid; i < 64 * 8; i += 256) {
            int m = i >> 3, q = i & 7;
            int rr = row0 + m;
            float4 v = (rr < n) ? *reinterpret_cast<const float4*>(X + (size_t)rr * K + k0 + q * 4)
                                : make_float4(0.f, 0.f, 0.f, 0.f);
            unsigned short h0 = f2bf(v.x), h1 = f2bf(v.y), h2 = f2bf(v.z), h3 = f2bf(v.w);
            unsigned short l0 = f2bf(v.x - bf2f(h0)), l1 = f2bf(v.y - bf2f(h1));
            unsigned short l2 = f2bf(v.z - bf2f(h2)), l3 = f2bf(v.w - bf2f(h3));
            uint2 ph = make_uint2((unsigned)h0 | ((unsigned)h1 << 16), (unsigned)h2 | ((unsigned)h3 << 16));
            uint2 pl = make_uint2((unsigned)l0 | ((unsigned)l1 << 16), (unsigned)l2 | ((unsigned)l3 << 16));
            *reinterpret_cast<uint2*>(&xh[m][q * 4]) = ph;
            *reinterpret_cast<uint2*>(&xl[m][q * 4]) = pl;
        }
        for (int i = tid; i < BN * 4; i += 256) {
            int cc = i >> 2, q = i & 3;
            size_t goff = (size_t)(col0 + cc) * K + k0 + q * 8;
            *reinterpret_cast<uint4*>(&wh[cc][q * 8]) = *reinterpret_cast<const uint4*>(Wh + goff);
            *reinterpret_cast<uint4*>(&wl[cc][q * 8]) = *reinterpret_cast<const uint4*>(Wl + goff);
        }
        __syncthreads();

        short8v ah = *reinterpret_cast<const short8v*>(&xh[wave * 16 + r_l][k_l]);
        short8v al = *reinterpret_cast<const short8v*>(&xl[wave * 16 + r_l][k_l]);
#pragma unroll
        for (int t = 0; t < NT; ++t) {
            short8v bh = *reinterpret_cast<const short8v*>(&wh[t * 16 + r_l][k_l]);
            short8v bl = *reinterpret_cast<const short8v*>(&wl[t * 16 + r_l][k_l]);
            acc[t] = __builtin_amdgcn_mfma_f32_16x16x32_bf16(ah, bh, acc[t], 0, 0, 0);
            acc[t] = __builtin_amdgcn_mfma_f32_16x16x32_bf16(al, bh, acc[t], 0, 0, 0);
            acc[t] = __builtin_amdgcn_mfma_f32_16x16x32_bf16(ah, bl, acc[t], 0, 0, 0);
        }
        __syncthreads();
    }

    const int orow = row0 + wave * 16 + (lane >> 4) * 4;
#pragma unroll
    for (int t = 0; t < NT; ++t) {
        int col = col0 + t * 16 + r_l;
        float s, tt, bias;
        if (MODE == 0 || MODE == 2) {
            float sv = g[col] * rsqrtf(rv[col] + EPS);
            s = sv; tt = be[col] - rm[col] * sv; bias = b[col];
        } else {
            s = g[col] * rsqrtf(rv[col] + EPS); tt = 0.f; bias = 0.f;
        }
#pragma unroll
        for (int r = 0; r < 4; ++r) {
            int rr = orow + r;
            if (rr < n) {
                float z = acc[t][r];
                if (MODE == 0)      { z = (z + bias) * s + tt; z = fmaxf(z, 0.0f); }
                else if (MODE == 1) { z = z * s; }
                else                { z = fmaxf(z + bias, 0.0f) * s + tt; }
                if (OUTBF) ((unsigned short*)outv)[(size_t)rr * DOUT + col] = f2bf(z);
                else       ((float*)outv)[(size_t)rr * DOUT + col] = z;
            }
        }
    }
}

// ---------------- f32 register-tiled GEMM (layer-1 + classifier) ----------------
template<int K, int DOUT, int MODE, int OUTBF>
__global__ __launch_bounds__(256) void gemm_tile(const float* __restrict__ X, const float* __restrict__ W,
                                                 const float* __restrict__ b, const float* __restrict__ g,
                                                 const float* __restrict__ be, const float* __restrict__ rm,
                                                 const float* __restrict__ rv, void* __restrict__ outv, int n) {
    constexpr int TM = 8;
    constexpr int TN = (DOUT >= 64) ? 8 : 4;
    constexpr int BN = (DOUT < 128) ? DOUT : 128;
    constexpr int BM = 256 * TM * TN / BN;
    constexpr int KT = (K % 32 == 0) ? 32 : K;
    constexpr int NTN = BN / TN;
    static_assert((BM / TM) * NTN == 256, "thread mapping");

    __shared__ float xs[BM][KT + 1];
    __shared__ float ws[KT][BN];

    const int tid = threadIdx.x;
    const int tn_idx = tid % NTN;
    const int tm_idx = tid / NTN;
    const int row0 = blockIdx.x * BM;
    const int col0 = blockIdx.y * BN;

    float acc[TM][TN];
#pragma unroll
    for (int i = 0; i < TM; ++i)
#pragma unroll
        for (int j = 0; j < TN; ++j) acc[i][j] = 0.0f;

    for (int k0 = 0; k0 < K; k0 += KT) {
        if (K % 4 == 0) {
            for (int i = tid; i < BM * KT / 4; i += 256) {
                int m = i / (KT / 4), kq = i - m * (KT / 4);
                int k = kq * 4;
                int rr = row0 + m;
                float4 v = (rr < n) ? *reinterpret_cast<const float4*>(X + (size_t)rr * K + k0 + k)
                                    : make_float4(0.f, 0.f, 0.f, 0.f);
                xs[m][k + 0] = v.x; xs[m][k + 1] = v.y; xs[m][k + 2] = v.z; xs[m][k + 3] = v.w;
            }
        } else {
            for (int i = tid; i < BM * KT / 2; i += 256) {
                int m = i / (KT / 2), kq = i - m * (KT / 2);
                int k = kq * 2;
                int rr = row0 + m;
                float2 v = (rr < n) ? *reinterpret_cast<const float2*>(X + (size_t)rr * K + k0 + k)
                                    : make_float2(0.f, 0.f);
                xs[m][k + 0] = v.x; xs[m][k + 1] = v.y;
            }
        }
        for (int i = tid; i < KT * BN / 4; i += 256) {
            int k = i / (BN / 4), cq = i - k * (BN / 4);
            float4 wv = *reinterpret_cast<const float4*>(W + (size_t)(k0 + k) * DOUT + col0 + cq * 4);
            *reinterpret_cast<float4*>(&ws[k][cq * 4]) = wv;
        }
        __syncthreads();

#pragma unroll 2
        for (int k = 0; k < KT; ++k) {
            float av[TM], bv[TN];
#pragma unroll
            for (int i = 0; i < TM; ++i) av[i] = xs[tm_idx * TM + i][k];
#pragma unroll
            for (int j = 0; j < TN; j += 4)
                *reinterpret_cast<float4*>(&bv[j]) = *reinterpret_cast<const float4*>(&ws[k][tn_idx * TN + j]);
#pragma unroll
            for (int i = 0; i < TM; ++i)
#pragma unroll
                for (int j = 0; j < TN; ++j)
                    acc[i][j] = fmaf(av[i], bv[j], acc[i][j]);
        }
        __syncthreads();
    }

    float s[TN], t[TN], bias[TN];
#pragma unroll
    for (int j = 0; j < TN; ++j) {
        int col = col0 + tn_idx * TN + j;
        if (MODE == 0 || MODE == 2) {
            float sv = g[col] * rsqrtf(rv[col] + EPS);
            s[j] = sv; t[j] = be[col] - rm[col] * sv; bias[j] = b[col];
        } else {
            s[j] = g[col] * rsqrtf(rv[col] + EPS); t[j] = 0.f; bias[j] = 0.f;
        }
    }

#pragma unroll
    for (int i = 0; i < TM; ++i) {
        int rr = row0 + tm_idx * TM + i;
        if (rr < n) {
            float o[TN];
#pragma unroll
            for (int j = 0; j < TN; ++j) {
                float z = acc[i][j];
                if (MODE == 0)      { z = (z + bias[j]) * s[j] + t[j]; z = fmaxf(z, 0.0f); }
                else if (MODE == 1) { z = z * s[j]; }
                else                { z = fmaxf(z + bias[j], 0.0f) * s[j] + t[j]; }
                o[j] = z;
            }
            if (OUTBF) {
                unsigned short* op = (unsigned short*)outv + (size_t)rr * DOUT + col0 + tn_idx * TN;
                unsigned int pk[TN / 2];
#pragma unroll
                for (int j2 = 0; j2 < TN / 2; ++j2)
                    pk[j2] = (unsigned)f2bf(o[2 * j2]) | ((unsigned)f2bf(o[2 * j2 + 1]) << 16);
#pragma unroll
                for (int j2 = 0; j2 < TN / 2; ++j2)
                    *reinterpret_cast<unsigned int*>(op + 2 * j2) = pk[j2];
            } else {
                float* op = (float*)outv + (size_t)rr * DOUT + col0 + tn_idx * TN;
#pragma unroll
                for (int j = 0; j < TN; j += 4)
                    *reinterpret_cast<float4*>(op + j) = *reinterpret_cast<const float4*>(&o[j]);
            }
        }
    }
}

// final Linear 32 -> 2
__global__ __launch_bounds__(256) void final_linear(const float* __restrict__ X, const float* __restrict__ W,
                                                    const float* __restrict__ b, float* __restrict__ out, int n) {
    int row = blockIdx.x * 256 + threadIdx.x;
    if (row >= n) return;
    float a0 = 0.0f, a1 = 0.0f;
#pragma unroll
    for (int k = 0; k < 32; ++k) {
        float xv = X[(size_t)row * 32 + k];
        a0 = fmaf(xv, W[k * 2 + 0], a0);
        a1 = fmaf(xv, W[k * 2 + 1], a1);
    }
    out[(size_t)row * 2 + 0] = a0 + b[0];
    out[(size_t)row * 2 + 1] = a1 + b[1];
}

// ---------------- launch ----------------

extern "C" void kernel_launch(void* const* d_in, const int* in_sizes, int n_in,
                              void* d_out, int out_size, void* d_ws, size_t ws_size,
                              hipStream_t stream) {
    const float* x  = (const float*)d_in[0];
    const int*   ei = (const int*)d_in[1];
    const int E = in_sizes[1] / 2;
    const int n = in_sizes[0] / 42;
    const int* src = ei;
    const int* dst = ei + E;

    const float *W1 = (const float*)d_in[2],  *b1 = (const float*)d_in[3],  *g1 = (const float*)d_in[4],
                *be1 = (const float*)d_in[5], *rm1 = (const float*)d_in[6], *rv1 = (const float*)d_in[7];
    const float *W2 = (const float*)d_in[8],  *b2 = (const float*)d_in[9],  *g2 = (const float*)d_in[10],
                *be2 = (const float*)d_in[11], *rm2 = (const float*)d_in[12], *rv2 = (const float*)d_in[13];
    const float *W3 = (const float*)d_in[14], *b3 = (const float*)d_in[15], *g3 = (const float*)d_in[16],
                *be3 = (const float*)d_in[17], *rm3 = (const float*)d_in[18], *rv3 = (const float*)d_in[19];
    const float *W4 = (const float*)d_in[20], *b4 = (const float*)d_in[21], *g4 = (const float*)d_in[22],
                *be4 = (const float*)d_in[23], *rm4 = (const float*)d_in[24], *rv4 = (const float*)d_in[25];
    const float *cW1 = (const float*)d_in[26], *cb1 = (const float*)d_in[27], *cg1 = (const float*)d_in[28],
                *cbe1 = (const float*)d_in[29], *crm1 = (const float*)d_in[30], *crv1 = (const float*)d_in[31];
    const float *cW2 = (const float*)d_in[32], *cb2 = (const float*)d_in[33], *cg2 = (const float*)d_in[34],
                *cbe2 = (const float*)d_in[35], *crm2 = (const float*)d_in[36], *crv2 = (const float*)d_in[37];
    const float *cW3 = (const float*)d_in[38], *cb3 = (const float*)d_in[39];

    // ---- workspace layout (16B-aligned blocks) ----
    int2*  csr    = (int2*)d_ws;                         // E
    float* bufA   = (float*)(csr + E);                   // n*128
    float* bufB   = bufA + (size_t)n * 128;              // n*256
    unsigned short* hbf = (unsigned short*)(bufB + (size_t)n * 256);  // n*128 bf16 (h1/h3/h4, disjoint lifetimes)
    float* dis    = (float*)(hbf + (size_t)n * 128);     // n
    int*   cnt    = (int*)(dis + n);                     // n
    int*   fill   = cnt + n;                             // n
    int*   rowptr = fill + n;                            // n+1
    int*   bsum   = rowptr + n + 1;                      // 256
    unsigned short* w2h = (unsigned short*)(bsum + 256); // 256*128
    unsigned short* w2l = w2h + 256 * 128;
    unsigned short* w3h = w2l + 256 * 128;               // 128*256
    unsigned short* w3l = w3h + 128 * 256;
    unsigned short* w4h = w3l + 128 * 256;               // 64*128
    unsigned short* w4l = w4h + 64 * 128;

    dim3 blk(256);
    auto nb = [](long total) { return dim3((unsigned)((total + 255) / 256)); };
    const int nscan = (n + 1023) / 1024;
    const float* nul = nullptr;

    // ---- CSR build + W splits ----
    hipMemsetAsync(cnt, 0, (size_t)2 * n * sizeof(int), stream);
    count_deg<<<nb(E), blk, 0, stream>>>(dst, cnt, E);
    calc_dis<<<nb(n), blk, 0, stream>>>(cnt, dis, n);
    scan1<<<dim3(nscan), blk, 0, stream>>>(cnt, rowptr, bsum, n);
    scan2<<<dim3(1), blk, 0, stream>>>(bsum, nscan);
    scan3<<<nb(n), blk, 0, stream>>>(rowptr, bsum, n, E);
    csr_fill<<<nb(E), blk, 0, stream>>>(src, dst, dis, rowptr, fill, csr, E);
    split_w<<<nb(256 * 128), blk, 0, stream>>>(W2, w2h, w2l, 128, 256, 128);
    split_w<<<nb(128 * 256), blk, 0, stream>>>(W3, w3h, w3l, 256, 128, 256);
    split_w<<<nb(64 * 128),  blk, 0, stream>>>(W4, w4h, w4l, 128, 64, 128);

    // ---- Layer 1 (aggregate-first, d=42, f32 gather): agg(x)->bufA; gemm 42->128 BN+ReLU -> hbf (bf16)
    agg_gather<42, 2, 0><<<nb((long)n * 21), blk, 0, stream>>>(x, dis, rowptr, csr, nul, nul, nul, nul, nul, bufA, n);
    gemm_tile<42, 128, 0, 1><<<dim3((n + 127) / 128, 1), blk, 0, stream>>>(bufA, W1, b1, g1, be1, rm1, rv1, (void*)hbf, n);

    // ---- Layer 2 (aggregate-first, d=128, bf16 gather): agg(hbf)->bufA; gemm 128->256 BN+ReLU -> bufB (f32)
    agg_bf<128, 0><<<nb((long)n * 16), blk, 0, stream>>>(hbf, dis, rowptr, csr, nul, nul, nul, nul, nul, bufA, n);
    gemm_mfma<128, 256, 0, 0><<<dim3((n + 63) / 64, 2), blk, 0, stream>>>(bufA, w2h, w2l, b2, g2, be2, rm2, rv2, (void*)bufB, n);

    // ---- Layer 3 (transform-first): gemm 256->128 (scale s) -> hbf (bf16); agg + fused bias/bn/relu -> bufA
    gemm_mfma<256, 128, 1, 1><<<dim3((n + 63) / 64, 1), blk, 0, stream>>>(bufB, w3h, w3l, b3, g3, be3, rm3, rv3, (void*)hbf, n);
    agg_bf<128, 1><<<nb((long)n * 16), blk, 0, stream>>>(hbf, dis, rowptr, csr, b3, g3, be3, rm3, rv3, bufA, n);

    // ---- Layer 4 (transform-first): gemm 128->64 (scale s) -> hbf (bf16); agg + fused bias/bn/relu -> bufB
    gemm_mfma<128, 64, 1, 1><<<dim3((n + 63) / 64, 1), blk, 0, stream>>>(bufA, w4h, w4l, b4, g4, be4, rm4, rv4, (void*)hbf, n);
    agg_bf<64, 1><<<nb((long)n * 8), blk, 0, stream>>>(hbf, dis, rowptr, csr, b4, g4, be4, rm4, rv4, bufB, n);

    // ---- Classifier
    gemm_tile<64, 64, 2, 0><<<dim3((n + 255) / 256, 1), blk, 0, stream>>>(bufB, cW1, cb1, cg1, cbe1, crm1, crv1, (void*)bufA, n);
    gemm_tile<64, 32, 2, 0><<<dim3((n + 255) / 256, 1), blk, 0, stream>>>(bufA, cW2, cb2, cg2, cbe2, crm2, crv2, (void*)bufB, n);
    final_linear<<<nb(n), blk, 0, stream>>>(bufB, cW3, cb3, (float*)d_out, n);
}